// Round 1
// baseline (3224.496 us; speedup 1.0000x reference)
//
#include <hip/hip_runtime.h>

#define TSZ 32768
#define LWN 98304

typedef float f32x4 __attribute__((ext_vector_type(4)));
typedef short s16x8 __attribute__((ext_vector_type(8)));
typedef unsigned short u16x8 __attribute__((ext_vector_type(8)));

__device__ __forceinline__ float leaky(float x) { return x > 0.f ? x : 0.2f * x; }
__device__ __forceinline__ float bf2f(unsigned short b) { return __uint_as_float(((unsigned)b) << 16); }
__device__ __forceinline__ unsigned short f2bf(float f) {
  unsigned u = __float_as_uint(f);
  u += 0x7fffu + ((u >> 16) & 1u);
  return (unsigned short)(u >> 16);
}

// ---------------- conv_transpose: h = convT(leaky(x)) + ct_b -----------------
// SAME, stride 8, K=16 -> pad 11/11 on dilated input; per t exactly 2 taps.
__global__ __launch_bounds__(256) void ct_kernel(const float* __restrict__ x,
                                                 const float* __restrict__ ct_w,
                                                 const float* __restrict__ ct_b,
                                                 float* __restrict__ h) {
  __shared__ float wl[2 * 64 * 64];
  __shared__ float xl[17 * 64];
  int bid = blockIdx.x;
  int qc = bid & 255, phi = (bid >> 8) & 7, b = bid >> 11;
  int w0 = (11 - phi) & 7;
  int d0 = (phi + w0 - 11) >> 3;  // -1 or 0
  int tid = threadIdx.x;
  for (int e = tid; e < 8192; e += 256) {
    int w2 = e >> 12, rest = e & 4095;
    wl[e] = ct_w[(w0 + 8 * w2) * 4096 + rest];
  }
  int mstart = qc * 16 + d0;
  for (int e = tid; e < 17 * 64; e += 256) {
    int mr = e >> 6, i = e & 63;
    int m = mstart + mr;
    xl[e] = (m >= 0 && m < 4096) ? leaky(x[((b << 12) + m) * 64 + i]) : 0.f;
  }
  __syncthreads();
  int o = tid & 63, tg4 = tid >> 6;
  float bv = ct_b[o];
  float acc[4] = {bv, bv, bv, bv};
  for (int w2 = 0; w2 < 2; w2++) {
    const float* wp = &wl[w2 * 4096];
    int rbase = tg4 * 4 + w2;
    const float* xp = &xl[rbase * 64];
    for (int i = 0; i < 64; i++) {
      float wv = wp[i * 64 + o];
      acc[0] += xp[i] * wv;
      acc[1] += xp[64 + i] * wv;
      acc[2] += xp[128 + i] * wv;
      acc[3] += xp[192 + i] * wv;
    }
  }
  for (int r = 0; r < 4; r++) {
    int t = (qc * 16 + tg4 * 4 + r) * 8 + phi;
    h[(((size_t)b << 15) + t) * 64 + o] = acc[r];
  }
}

// ---------------- conditioning network (tiny) -----------------
__global__ __launch_bounds__(256) void conv5_kernel(const float* __restrict__ c,
                                                    const float* __restrict__ w,
                                                    const float* __restrict__ bias,
                                                    float* __restrict__ cc) {
  int f = blockIdx.x * 256 + threadIdx.x;  // 32768
  int o = f & 63, t = (f >> 6) & 127, b = f >> 13;
  float acc = bias[o];
  for (int kk = 0; kk < 5; kk++) {
    int tt = t + kk - 2;
    if (tt < 0 || tt >= 128) continue;
    const float* cr = c + (b * 128 + tt) * 80;
    const float* wr = w + kk * 80 * 64 + o;
    for (int i = 0; i < 80; i++) acc += cr[i] * wr[i * 64];
  }
  cc[f] = leaky(acc);
}

template <int ADD>
__global__ __launch_bounds__(256) void conv3_kernel(const float* __restrict__ xin,
                                                    const float* __restrict__ w,
                                                    const float* __restrict__ bias,
                                                    const float* __restrict__ addsrc,
                                                    float* __restrict__ out) {
  int f = blockIdx.x * 256 + threadIdx.x;  // 32768
  int o = f & 63, t = (f >> 6) & 127, b = f >> 13;
  float acc = bias[o];
  for (int kk = 0; kk < 3; kk++) {
    int tt = t + kk - 1;
    if (tt < 0 || tt >= 128) continue;
    const float* xr = xin + (b * 128 + tt) * 64;
    const float* wr = w + kk * 64 * 64 + o;
    for (int i = 0; i < 64; i++) acc += xr[i] * wr[i * 64];
  }
  float v = leaky(acc);
  if (ADD) v += addsrc[f];
  out[f] = v;
}

// ---------------- im2col patches for the prediction GEMMs -----------------
__global__ __launch_bounds__(256) void patch_kernel(const float* __restrict__ cc,
                                                    float* __restrict__ A) {
  int f = blockIdx.x * 256 + threadIdx.x;  // 98304
  int k = f % 192, m = f / 192;
  int b = m >> 7, l = m & 127;
  int kk = k >> 6, hh = k & 63;
  int ll = l + kk - 1;
  A[f] = (ll >= 0 && ll < 128) ? cc[((b << 7) + ll) * 64 + hh] : 0.f;
}

__global__ __launch_bounds__(256) void bbgemm_kernel(const float* __restrict__ A,
                                                     const float* __restrict__ w,
                                                     const float* __restrict__ bias,
                                                     float* __restrict__ bb) {
  int f = blockIdx.x * 256 + threadIdx.x;  // 262144
  int n = f & 511, m = f >> 9;
  float acc = bias[n];
  const float* ar = A + m * 192;
  const float* wr = w + n;
  for (int k = 0; k < 192; k++) acc += ar[k] * wr[k * 512];
  bb[f] = acc;
}

// ---------------- pre-swizzle W and A into MFMA fragment layout (bf16) ----------
// frag layout: [(tile)*6+kf][lane][j], lane = ((k&31)>>3)*16 + (idx&15), j = k&7
__global__ __launch_bounds__(256) void wreorg_kernel(const float* __restrict__ W,
                                                     unsigned short* __restrict__ Wf) {
  int ft = blockIdx.x * 256 + threadIdx.x;  // 2359296
  int lane = ft & 63, fragid = ft >> 6;
  int kf = fragid % 6, nt = fragid / 6;
  int col = lane & 15, q = lane >> 4;
  int n = nt * 16 + col;
  u16x8 v;
  for (int j = 0; j < 8; j++) {
    int kki = kf * 32 + q * 8 + j;
    v[j] = f2bf(W[(size_t)kki * LWN + n]);
  }
  *(u16x8*)(Wf + ((size_t)fragid * 64 + lane) * 8) = v;
}

__global__ __launch_bounds__(256) void afrag_kernel(const float* __restrict__ A,
                                                    unsigned short* __restrict__ Af) {
  int ft = blockIdx.x * 256 + threadIdx.x;  // 12288
  int lane = ft & 63, fragid = ft >> 6;
  int kf = fragid % 6, mt = fragid / 6;
  int row = lane & 15, q = lane >> 4;
  const float* ar = A + (mt * 16 + row) * 192 + kf * 32 + q * 8;
  u16x8 v;
  for (int j = 0; j < 8; j++) v[j] = f2bf(ar[j]);
  *(u16x8*)(Af + ((size_t)fragid * 64 + lane) * 8) = v;
}

// ---------------- k = A @ W + kern_b  (M=512, N=98304, K=192), bf16 MFMA ----------
__global__ __launch_bounds__(256) void kgemm_kernel(const unsigned short* __restrict__ Af,
                                                    const unsigned short* __restrict__ Wf,
                                                    const float* __restrict__ kern_b,
                                                    unsigned short* __restrict__ kb) {
  int wave = threadIdx.x >> 6, lane = threadIdx.x & 63;
  int col = lane & 15, q = lane >> 4;
  int mt0 = blockIdx.y * 16 + wave * 4;
  int nt0 = blockIdx.x * 4;
  f32x4 acc[4][4];
  for (int a = 0; a < 4; a++)
    for (int cg = 0; cg < 4; cg++) acc[a][cg] = (f32x4){0.f, 0.f, 0.f, 0.f};
  const s16x8* ap = (const s16x8*)Af;
  const s16x8* bp = (const s16x8*)Wf;
  for (int kf = 0; kf < 6; kf++) {
    s16x8 av[4], bv[4];
    for (int a = 0; a < 4; a++) av[a] = ap[((mt0 + a) * 6 + kf) * 64 + lane];
    for (int cg = 0; cg < 4; cg++) bv[cg] = bp[((size_t)(nt0 + cg) * 6 + kf) * 64 + lane];
    for (int a = 0; a < 4; a++)
      for (int cg = 0; cg < 4; cg++)
        acc[a][cg] = __builtin_amdgcn_mfma_f32_16x16x32_bf16(av[a], bv[cg], acc[a][cg], 0, 0, 0);
  }
  for (int cg = 0; cg < 4; cg++) {
    int n = (nt0 + cg) * 16 + col;
    float bias = kern_b[n];
    for (int a = 0; a < 4; a++) {
      int mbase = (mt0 + a) * 16 + q * 4;
      for (int r = 0; r < 4; r++)
        kb[(size_t)(mbase + r) * LWN + n] = f2bf(acc[a][cg][r] + bias);
    }
  }
}

// ---------------- per-layer dilated conv: xc = leaky(conv3_dil(leaky(h))) ----------
__global__ __launch_bounds__(256) void dconv_kernel(const float* __restrict__ h,
                                                    const float* __restrict__ conv_w,
                                                    const float* __restrict__ conv_b,
                                                    float* __restrict__ xc, int lay, int d) {
  __shared__ unsigned short wl[3 * 64 * 64];  // bf16 weights
  __shared__ float xl[70 * 64];               // leaky(h) tile
  int tid = threadIdx.x;
  int bt0 = blockIdx.x * 16;
  int b = bt0 >> 15, t0 = bt0 & 32767;
  const float* wsrc = conv_w + lay * 12288;
  for (int e = tid; e < 12288; e += 256) wl[e] = f2bf(wsrc[e]);
  int rows = 16 + 2 * d;
  const float* hb = h + (((size_t)b) << 15) * 64;
  for (int e = tid; e < rows * 64; e += 256) {
    int tr = e >> 6, i = e & 63;
    int tt = t0 - d + tr;
    xl[e] = (tt >= 0 && tt < TSZ) ? leaky(hb[(size_t)tt * 64 + i]) : 0.f;
  }
  __syncthreads();
  int o = tid & 63, tg4 = tid >> 6;
  float bv = conv_b[lay * 64 + o];
  float acc[4] = {bv, bv, bv, bv};
  for (int kk = 0; kk < 3; kk++) {
    const unsigned short* wp = wl + kk * 4096 + o;
    const float* xp = xl + (tg4 * 4 + kk * d) * 64;
    for (int i = 0; i < 64; i++) {
      float wv = bf2f(wp[i * 64]);
      acc[0] += xp[i] * wv;
      acc[1] += xp[64 + i] * wv;
      acc[2] += xp[128 + i] * wv;
      acc[3] += xp[192 + i] * wv;
    }
  }
  float* xb = xc + ((((size_t)b) << 15) + t0) * 64;
  for (int r = 0; r < 4; r++) xb[(tg4 * 4 + r) * 64 + o] = leaky(acc[r]);
}

// ---------------- LVC + gate + residual h update (one block per (b,l)) ----------
__global__ __launch_bounds__(256) void lvc_kernel(const float* __restrict__ xc,
                                                  const unsigned short* __restrict__ kb,
                                                  const float* __restrict__ bb,
                                                  float* __restrict__ h, int lay) {
  __shared__ float kl[3 * 128 * 65];         // 99840 B, pad 65 breaks bank conflicts
  __shared__ unsigned short p0[258 * 64];    // 33024 B  (patch rows, bf16)
  int tid = threadIdx.x;
  int l = blockIdx.x & 127, b = blockIdx.x >> 7;
  size_t kbase = ((size_t)(b * 128 + lay * 32 + (l >> 2))) * LWN + (l & 3) * 24576;
  for (int e = tid; e < 24576; e += 256) {
    int i = e / 384;
    int rem = e - i * 384;
    int o = rem / 3;
    int kk = rem - o * 3;
    kl[(kk * 128 + o) * 65 + i] = bf2f(kb[kbase + e]);
  }
  int tbase = l * 256 - 1;
  const float* xb = xc + (((size_t)b) << 15) * 64;
  for (int e = tid; e < 258 * 64; e += 256) {
    int n = e >> 6, i = e & 63;
    int tt = tbase + n;
    p0[e] = f2bf((tt >= 0 && tt < TSZ) ? xb[(size_t)tt * 64 + i] : 0.f);
  }
  __syncthreads();
  int och = tid & 63, sgrp = tid >> 6;
  int bidx = (b * 128 + lay * 32 + (l >> 2)) * 512 + (l & 3) * 128 + och;
  float bias0 = bb[bidx], bias1 = bb[bidx + 64];
  float* hbase = h + ((((size_t)b) << 15) + l * 256) * 64;
  for (int j = 0; j < 64; j++) {
    int s = sgrp * 64 + j;
    float acc0 = bias0, acc1 = bias1;
    for (int kk = 0; kk < 3; kk++) {
      int nr = 3 * s + kk - 255;
      int n = nr < 0 ? -nr : (nr >= 258 ? 514 - nr : nr);  // reflect pad
      const unsigned* prow = (const unsigned*)(p0 + n * 64);
      const float* w0 = kl + (kk * 128 + och) * 65;
      const float* w1 = w0 + 64 * 65;
#pragma unroll
      for (int i2 = 0; i2 < 32; i2++) {
        unsigned u = prow[i2];
        float pa = __uint_as_float(u << 16);
        float pb = __uint_as_float(u & 0xffff0000u);
        acc0 += pa * w0[2 * i2] + pb * w0[2 * i2 + 1];
        acc1 += pa * w1[2 * i2] + pb * w1[2 * i2 + 1];
      }
    }
    float sg = 1.f / (1.f + __expf(-acc0));
    float ex = __expf(2.f * acc1);
    float th = 1.f - 2.f / (ex + 1.f);
    hbase[(size_t)s * 64 + och] += sg * th;
  }
}

extern "C" void kernel_launch(void* const* d_in, const int* in_sizes, int n_in,
                              void* d_out, int out_size, void* d_ws, size_t ws_size,
                              hipStream_t stream) {
  (void)in_sizes; (void)n_in; (void)out_size; (void)ws_size;
  const float* x      = (const float*)d_in[0];
  const float* c      = (const float*)d_in[1];
  const float* ct_w   = (const float*)d_in[2];
  const float* ct_b   = (const float*)d_in[3];
  const float* conv_w = (const float*)d_in[4];
  const float* conv_b = (const float*)d_in[5];
  const float* inp_w  = (const float*)d_in[6];
  const float* inp_b  = (const float*)d_in[7];
  const float* res_w1 = (const float*)d_in[8];
  const float* res_b1 = (const float*)d_in[9];
  const float* res_w2 = (const float*)d_in[10];
  const float* res_b2 = (const float*)d_in[11];
  const float* kern_w = (const float*)d_in[12];
  const float* kern_b = (const float*)d_in[13];
  const float* bias_w = (const float*)d_in[14];
  const float* bias_b = (const float*)d_in[15];

  float* h = (float*)d_out;  // h lives in d_out (fully written by ct_kernel)
  char* ws = (char*)d_ws;
  // region [0, 37748736): Wf during GEMM phase, then reused as xc in layer phase
  unsigned short* Wf = (unsigned short*)(ws);
  float* xc          = (float*)(ws);
  unsigned short* kb = (unsigned short*)(ws + 37748736);   // 100663296 B
  float* A           = (float*)(ws + 138412032);           // 393216 B
  unsigned short* Af = (unsigned short*)(ws + 138805248);  // 196608 B
  float* cc          = (float*)(ws + 139001856);           // 131072 B
  float* t1          = (float*)(ws + 139132928);           // 131072 B
  float* bbv         = (float*)(ws + 139264000);           // 1048576 B

  ct_kernel<<<dim3(8192), dim3(256), 0, stream>>>(x, ct_w, ct_b, h);
  conv5_kernel<<<dim3(128), dim3(256), 0, stream>>>(c, inp_w, inp_b, cc);
  for (int j = 0; j < 3; j++) {
    conv3_kernel<0><<<dim3(128), dim3(256), 0, stream>>>(cc, res_w1 + j * 12288, res_b1 + j * 64,
                                                         (const float*)nullptr, t1);
    conv3_kernel<1><<<dim3(128), dim3(256), 0, stream>>>(t1, res_w2 + j * 12288, res_b2 + j * 64,
                                                         cc, cc);
  }
  patch_kernel<<<dim3(384), dim3(256), 0, stream>>>(cc, A);
  bbgemm_kernel<<<dim3(1024), dim3(256), 0, stream>>>(A, bias_w, bias_b, bbv);
  wreorg_kernel<<<dim3(9216), dim3(256), 0, stream>>>(kern_w, Wf);
  afrag_kernel<<<dim3(48), dim3(256), 0, stream>>>(A, Af);
  kgemm_kernel<<<dim3(1536, 2), dim3(256), 0, stream>>>(Af, Wf, kern_b, kb);

  const int dil[4] = {1, 3, 9, 27};
  for (int lay = 0; lay < 4; lay++) {
    dconv_kernel<<<dim3(8192), dim3(256), 0, stream>>>(h, conv_w, conv_b, xc, lay, dil[lay]);
    lvc_kernel<<<dim3(512), dim3(256), 0, stream>>>(xc, kb, bbv, h, lay);
  }
}

// Round 2
// 1393.757 us; speedup vs baseline: 2.3135x; 2.3135x over previous
//
#include <hip/hip_runtime.h>

#define TSZ 32768
#define LWN 98304

typedef float f32x4 __attribute__((ext_vector_type(4)));
typedef short s16x8 __attribute__((ext_vector_type(8)));
typedef unsigned short u16x8 __attribute__((ext_vector_type(8)));

__device__ __forceinline__ float leaky(float x) { return x > 0.f ? x : 0.2f * x; }
__device__ __forceinline__ float bf2f(unsigned short b) { return __uint_as_float(((unsigned)b) << 16); }
__device__ __forceinline__ unsigned short f2bf(float f) {
  unsigned u = __float_as_uint(f);
  u += 0x7fffu + ((u >> 16) & 1u);
  return (unsigned short)(u >> 16);
}

// ---------------- conv_transpose: h = convT(leaky(x)) + ct_b -----------------
__global__ __launch_bounds__(256) void ct_kernel(const float* __restrict__ x,
                                                 const float* __restrict__ ct_w,
                                                 const float* __restrict__ ct_b,
                                                 float* __restrict__ h) {
  __shared__ float wl[2 * 64 * 64];
  __shared__ float xl[17 * 64];
  int bid = blockIdx.x;
  int qc = bid & 255, phi = (bid >> 8) & 7, b = bid >> 11;
  int w0 = (11 - phi) & 7;
  int d0 = (phi + w0 - 11) >> 3;  // -1 or 0
  int tid = threadIdx.x;
  for (int e = tid; e < 8192; e += 256) {
    int w2 = e >> 12, rest = e & 4095;
    wl[e] = ct_w[(w0 + 8 * w2) * 4096 + rest];
  }
  int mstart = qc * 16 + d0;
  for (int e = tid; e < 17 * 64; e += 256) {
    int mr = e >> 6, i = e & 63;
    int m = mstart + mr;
    xl[e] = (m >= 0 && m < 4096) ? leaky(x[((b << 12) + m) * 64 + i]) : 0.f;
  }
  __syncthreads();
  int o = tid & 63, tg4 = tid >> 6;
  float bv = ct_b[o];
  float acc[4] = {bv, bv, bv, bv};
  for (int w2 = 0; w2 < 2; w2++) {
    const float* wp = &wl[w2 * 4096];
    int rbase = tg4 * 4 + w2;
    const float* xp = &xl[rbase * 64];
    for (int i = 0; i < 64; i++) {
      float wv = wp[i * 64 + o];
      acc[0] += xp[i] * wv;
      acc[1] += xp[64 + i] * wv;
      acc[2] += xp[128 + i] * wv;
      acc[3] += xp[192 + i] * wv;
    }
  }
  for (int r = 0; r < 4; r++) {
    int t = (qc * 16 + tg4 * 4 + r) * 8 + phi;
    h[(((size_t)b << 15) + t) * 64 + o] = acc[r];
  }
}

// ---------------- conditioning network (tiny) -----------------
__global__ __launch_bounds__(256) void conv5_kernel(const float* __restrict__ c,
                                                    const float* __restrict__ w,
                                                    const float* __restrict__ bias,
                                                    float* __restrict__ cc) {
  int f = blockIdx.x * 256 + threadIdx.x;  // 32768
  int o = f & 63, t = (f >> 6) & 127, b = f >> 13;
  float acc = bias[o];
  for (int kk = 0; kk < 5; kk++) {
    int tt = t + kk - 2;
    if (tt < 0 || tt >= 128) continue;
    const float* cr = c + (b * 128 + tt) * 80;
    const float* wr = w + kk * 80 * 64 + o;
    for (int i = 0; i < 80; i++) acc += cr[i] * wr[i * 64];
  }
  cc[f] = leaky(acc);
}

template <int ADD>
__global__ __launch_bounds__(256) void conv3_kernel(const float* __restrict__ xin,
                                                    const float* __restrict__ w,
                                                    const float* __restrict__ bias,
                                                    const float* __restrict__ addsrc,
                                                    float* __restrict__ out) {
  int f = blockIdx.x * 256 + threadIdx.x;  // 32768
  int o = f & 63, t = (f >> 6) & 127, b = f >> 13;
  float acc = bias[o];
  for (int kk = 0; kk < 3; kk++) {
    int tt = t + kk - 1;
    if (tt < 0 || tt >= 128) continue;
    const float* xr = xin + (b * 128 + tt) * 64;
    const float* wr = w + kk * 64 * 64 + o;
    for (int i = 0; i < 64; i++) acc += xr[i] * wr[i * 64];
  }
  float v = leaky(acc);
  if (ADD) v += addsrc[f];
  out[f] = v;
}

// ---------------- im2col patches for the prediction GEMMs -----------------
__global__ __launch_bounds__(256) void patch_kernel(const float* __restrict__ cc,
                                                    float* __restrict__ A) {
  int f = blockIdx.x * 256 + threadIdx.x;  // 98304
  int k = f % 192, m = f / 192;
  int b = m >> 7, l = m & 127;
  int kk = k >> 6, hh = k & 63;
  int ll = l + kk - 1;
  A[f] = (ll >= 0 && ll < 128) ? cc[((b << 7) + ll) * 64 + hh] : 0.f;
}

__global__ __launch_bounds__(256) void bbgemm_kernel(const float* __restrict__ A,
                                                     const float* __restrict__ w,
                                                     const float* __restrict__ bias,
                                                     float* __restrict__ bb) {
  int f = blockIdx.x * 256 + threadIdx.x;  // 262144
  int n = f & 511, m = f >> 9;
  float acc = bias[n];
  const float* ar = A + m * 192;
  const float* wr = w + n;
  for (int k = 0; k < 192; k++) acc += ar[k] * wr[k * 512];
  bb[f] = acc;
}

// ---------------- pre-swizzle W and A into MFMA fragment layout (bf16) ----------
__global__ __launch_bounds__(256) void wreorg_kernel(const float* __restrict__ W,
                                                     unsigned short* __restrict__ Wf) {
  int ft = blockIdx.x * 256 + threadIdx.x;  // 2359296
  int lane = ft & 63, fragid = ft >> 6;
  int kf = fragid % 6, nt = fragid / 6;
  int col = lane & 15, q = lane >> 4;
  int n = nt * 16 + col;
  u16x8 v;
  for (int j = 0; j < 8; j++) {
    int kki = kf * 32 + q * 8 + j;
    v[j] = f2bf(W[(size_t)kki * LWN + n]);
  }
  *(u16x8*)(Wf + ((size_t)fragid * 64 + lane) * 8) = v;
}

__global__ __launch_bounds__(256) void afrag_kernel(const float* __restrict__ A,
                                                    unsigned short* __restrict__ Af) {
  int ft = blockIdx.x * 256 + threadIdx.x;  // 12288
  int lane = ft & 63, fragid = ft >> 6;
  int kf = fragid % 6, mt = fragid / 6;
  int row = lane & 15, q = lane >> 4;
  const float* ar = A + (mt * 16 + row) * 192 + kf * 32 + q * 8;
  u16x8 v;
  for (int j = 0; j < 8; j++) v[j] = f2bf(ar[j]);
  *(u16x8*)(Af + ((size_t)fragid * 64 + lane) * 8) = v;
}

// ---------------- k = A @ W + kern_b  (M=512, N=98304, K=192), bf16 MFMA ----------
// Output written DIRECTLY in per-(b,lay,l) B-fragment layout for lvc:
//   kbf[(((b*4+lay)*128+l)*48 + nt*6+kf)*512 + lane*8 + j]
//   where k_idx = kk*64+i, n-col = o: nt=o>>4, lane=((k_idx>>3)&3)*16 + (o&15),
//   kf=k_idx>>5, j=k_idx&7.
__global__ __launch_bounds__(256) void kgemm_kernel(const unsigned short* __restrict__ Af,
                                                    const unsigned short* __restrict__ Wf,
                                                    const float* __restrict__ kern_b,
                                                    unsigned short* __restrict__ kbf) {
  int wave = threadIdx.x >> 6, lane = threadIdx.x & 63;
  int col = lane & 15, q = lane >> 4;
  int mt0 = blockIdx.y * 16 + wave * 4;
  int nt0 = blockIdx.x * 4;
  f32x4 acc[4][4];
  for (int a = 0; a < 4; a++)
    for (int cg = 0; cg < 4; cg++) acc[a][cg] = (f32x4){0.f, 0.f, 0.f, 0.f};
  const s16x8* ap = (const s16x8*)Af;
  const s16x8* bp = (const s16x8*)Wf;
  for (int kf = 0; kf < 6; kf++) {
    s16x8 av[4], bv[4];
    for (int a = 0; a < 4; a++) av[a] = ap[((mt0 + a) * 6 + kf) * 64 + lane];
    for (int cg = 0; cg < 4; cg++) bv[cg] = bp[((size_t)(nt0 + cg) * 6 + kf) * 64 + lane];
    for (int a = 0; a < 4; a++)
      for (int cg = 0; cg < 4; cg++)
        acc[a][cg] = __builtin_amdgcn_mfma_f32_16x16x32_bf16(av[a], bv[cg], acc[a][cg], 0, 0, 0);
  }
  for (int cg = 0; cg < 4; cg++) {
    int n = (nt0 + cg) * 16 + col;
    float bias = kern_b[n];
    // decompose n -> (l2, i, o, kk) -> fragment coords
    int l2 = n / 24576;
    int rem = n - l2 * 24576;
    int i = rem / 384;
    int rem2 = rem - i * 384;
    int o = rem2 / 3;
    int kk = rem2 - o * 3;
    int k_idx = kk * 64 + i;
    int kf2 = k_idx >> 5, qq2 = (k_idx >> 3) & 3, j = k_idx & 7;
    int nt = o >> 4, lanec = qq2 * 16 + (o & 15);
    size_t fragoff = (size_t)(nt * 6 + kf2) * 512 + lanec * 8 + j;
    for (int a = 0; a < 4; a++) {
      int mbase = (mt0 + a) * 16 + q * 4;
      for (int r = 0; r < 4; r++) {
        int m = mbase + r;
        int bb_ = m >> 7, layl = m & 127;
        int lay = layl >> 5, lq = layl & 31;
        int l = lq * 4 + l2;
        size_t base = (size_t)((bb_ * 4 + lay) * 128 + l) * 24576;
        kbf[base + fragoff] = f2bf(acc[a][cg][r] + bias);
      }
    }
  }
}

// ---------------- per-layer dilated conv: xc = bf16(leaky(conv3_dil(leaky(h)))) ----
__global__ __launch_bounds__(256) void dconv_kernel(const float* __restrict__ h,
                                                    const float* __restrict__ conv_w,
                                                    const float* __restrict__ conv_b,
                                                    unsigned short* __restrict__ xc, int lay, int d) {
  __shared__ unsigned short wl[3 * 64 * 64];  // bf16 weights
  __shared__ float xl[70 * 64];               // leaky(h) tile
  int tid = threadIdx.x;
  int bt0 = blockIdx.x * 16;
  int b = bt0 >> 15, t0 = bt0 & 32767;
  const float* wsrc = conv_w + lay * 12288;
  for (int e = tid; e < 12288; e += 256) wl[e] = f2bf(wsrc[e]);
  int rows = 16 + 2 * d;
  const float* hb = h + (((size_t)b) << 15) * 64;
  for (int e = tid; e < rows * 64; e += 256) {
    int tr = e >> 6, i = e & 63;
    int tt = t0 - d + tr;
    xl[e] = (tt >= 0 && tt < TSZ) ? leaky(hb[(size_t)tt * 64 + i]) : 0.f;
  }
  __syncthreads();
  int o = tid & 63, tg4 = tid >> 6;
  float bv = conv_b[lay * 64 + o];
  float acc[4] = {bv, bv, bv, bv};
  for (int kk = 0; kk < 3; kk++) {
    const unsigned short* wp = wl + kk * 4096 + o;
    const float* xp = xl + (tg4 * 4 + kk * d) * 64;
    for (int i = 0; i < 64; i++) {
      float wv = bf2f(wp[i * 64]);
      acc[0] += xp[i] * wv;
      acc[1] += xp[64 + i] * wv;
      acc[2] += xp[128 + i] * wv;
      acc[3] += xp[192 + i] * wv;
    }
  }
  unsigned short* xb = xc + ((((size_t)b) << 15) + t0) * 64;
  for (int r = 0; r < 4; r++) xb[(tg4 * 4 + r) * 64 + o] = f2bf(leaky(acc[r]));
}

// ---------------- LVC as per-(b,l) MFMA GEMM: M=256, N=128, K=192 ----------------
// 512 threads = 8 waves, tiled 4(M) x 2(N); wave tile 64x64 via 16 mfma acc tiles.
// No LDS, no barriers. A-frags: reflect-indexed 16B loads from bf16 xc.
// B-frags: coalesced 16B loads from fragment-layout kbf (each element read once).
// Wave's N tiles = {2wn, 2wn+1, 2wn+4, 2wn+5} so (o, o+64) pair in same lane.
__global__ __launch_bounds__(512) void lvc_kernel(const unsigned short* __restrict__ xc,
                                                  const unsigned short* __restrict__ kbf,
                                                  const float* __restrict__ bbv,
                                                  float* __restrict__ h, int lay) {
  int tid = threadIdx.x;
  int l = blockIdx.x & 127, b = blockIdx.x >> 7;
  int w = tid >> 6, lane = tid & 63;
  int wm = w & 3, wn = w >> 2;
  int col = lane & 15, qq = lane >> 4;
  const s16x8* bbase = (const s16x8*)(kbf + (size_t)((b * 4 + lay) * 128 + l) * 24576);
  const unsigned short* xb = xc + (((size_t)b) << 15) * 64;

  f32x4 acc[4][4];
  for (int mt = 0; mt < 4; mt++)
    for (int cg = 0; cg < 4; cg++) acc[mt][cg] = (f32x4){0.f, 0.f, 0.f, 0.f};

  s16x8 av[2][4], bv[2][4];
  const s16x8 zfrag = {0, 0, 0, 0, 0, 0, 0, 0};

  // fragment loaders for step kf into buffer slot p
#define LOAD_STEP(p, kf)                                                            \
  {                                                                                 \
    int k0 = (kf) * 32 + qq * 8;                                                    \
    int kk = k0 >> 6, i0 = k0 & 63;                                                 \
    _Pragma("unroll") for (int mt = 0; mt < 4; mt++) {                              \
      int s = wm * 64 + mt * 16 + col;                                              \
      int nr = 3 * s + kk - 255;                                                    \
      int n = nr < 0 ? -nr : (nr >= 258 ? 514 - nr : nr);                           \
      int t = l * 256 + n - 1;                                                      \
      bool oob = ((unsigned)t >= (unsigned)TSZ);                                    \
      int tc = oob ? 0 : t;                                                         \
      s16x8 v = *(const s16x8*)(xb + (size_t)tc * 64 + i0);                         \
      av[p][mt] = oob ? zfrag : v;                                                  \
    }                                                                               \
    _Pragma("unroll") for (int cg = 0; cg < 4; cg++) {                              \
      int nt = 2 * wn + (cg & 1) + ((cg >> 1) << 2);                                \
      bv[p][cg] = bbase[(nt * 6 + (kf)) * 64 + lane];                               \
    }                                                                               \
  }

  LOAD_STEP(0, 0)
#pragma unroll
  for (int kf = 0; kf < 6; kf++) {
    int cur = kf & 1, nxt = cur ^ 1;
    if (kf < 5) LOAD_STEP(nxt, kf + 1)
#pragma unroll
    for (int mt = 0; mt < 4; mt++)
#pragma unroll
      for (int cg = 0; cg < 4; cg++)
        acc[mt][cg] =
            __builtin_amdgcn_mfma_f32_16x16x32_bf16(av[cur][mt], bv[cur][cg], acc[mt][cg], 0, 0, 0);
  }
#undef LOAD_STEP

  // epilogue: bias + sigmoid*tanh gate + h residual update
  int lq = l >> 2, l2 = l & 3;
  const float* bb0 = bbv + (size_t)(b * 128 + lay * 32 + lq) * 512 + l2 * 128;
  float* hb = h + ((((size_t)b) << 15) + l * 256) * 64;
#pragma unroll
  for (int mt = 0; mt < 4; mt++) {
#pragma unroll
    for (int p = 0; p < 2; p++) {
      int o = (2 * wn + p) * 16 + col;
      float b0 = bb0[o], b1 = bb0[o + 64];
#pragma unroll
      for (int r = 0; r < 4; r++) {
        int s = wm * 64 + mt * 16 + qq * 4 + r;
        float a0 = acc[mt][p][r] + b0;
        float a1 = acc[mt][p + 2][r] + b1;
        float sg = 1.f / (1.f + __expf(-a0));
        float ex = __expf(2.f * a1);
        float th = 1.f - 2.f / (ex + 1.f);
        hb[(size_t)s * 64 + o] += sg * th;
      }
    }
  }
}

extern "C" void kernel_launch(void* const* d_in, const int* in_sizes, int n_in,
                              void* d_out, int out_size, void* d_ws, size_t ws_size,
                              hipStream_t stream) {
  (void)in_sizes; (void)n_in; (void)out_size; (void)ws_size;
  const float* x      = (const float*)d_in[0];
  const float* c      = (const float*)d_in[1];
  const float* ct_w   = (const float*)d_in[2];
  const float* ct_b   = (const float*)d_in[3];
  const float* conv_w = (const float*)d_in[4];
  const float* conv_b = (const float*)d_in[5];
  const float* inp_w  = (const float*)d_in[6];
  const float* inp_b  = (const float*)d_in[7];
  const float* res_w1 = (const float*)d_in[8];
  const float* res_b1 = (const float*)d_in[9];
  const float* res_w2 = (const float*)d_in[10];
  const float* res_b2 = (const float*)d_in[11];
  const float* kern_w = (const float*)d_in[12];
  const float* kern_b = (const float*)d_in[13];
  const float* bias_w = (const float*)d_in[14];
  const float* bias_b = (const float*)d_in[15];

  float* h = (float*)d_out;  // h lives in d_out (fully written by ct_kernel)
  char* ws = (char*)d_ws;
  // region [0, 37748736): Wf during GEMM phase, then reused as bf16 xc in layer phase
  unsigned short* Wf = (unsigned short*)(ws);
  unsigned short* xc = (unsigned short*)(ws);
  unsigned short* kb = (unsigned short*)(ws + 37748736);   // 100663296 B (fragment layout)
  float* A           = (float*)(ws + 138412032);           // 393216 B
  unsigned short* Af = (unsigned short*)(ws + 138805248);  // 196608 B
  float* cc          = (float*)(ws + 139001856);           // 131072 B
  float* t1          = (float*)(ws + 139132928);           // 131072 B
  float* bbv         = (float*)(ws + 139264000);           // 1048576 B

  ct_kernel<<<dim3(8192), dim3(256), 0, stream>>>(x, ct_w, ct_b, h);
  conv5_kernel<<<dim3(128), dim3(256), 0, stream>>>(c, inp_w, inp_b, cc);
  for (int j = 0; j < 3; j++) {
    conv3_kernel<0><<<dim3(128), dim3(256), 0, stream>>>(cc, res_w1 + j * 12288, res_b1 + j * 64,
                                                         (const float*)nullptr, t1);
    conv3_kernel<1><<<dim3(128), dim3(256), 0, stream>>>(t1, res_w2 + j * 12288, res_b2 + j * 64,
                                                         cc, cc);
  }
  patch_kernel<<<dim3(384), dim3(256), 0, stream>>>(cc, A);
  bbgemm_kernel<<<dim3(1024), dim3(256), 0, stream>>>(A, bias_w, bias_b, bbv);
  wreorg_kernel<<<dim3(9216), dim3(256), 0, stream>>>(kern_w, Wf);
  afrag_kernel<<<dim3(48), dim3(256), 0, stream>>>(A, Af);
  kgemm_kernel<<<dim3(1536, 2), dim3(256), 0, stream>>>(Af, Wf, kern_b, kb);

  const int dil[4] = {1, 3, 9, 27};
  for (int lay = 0; lay < 4; lay++) {
    dconv_kernel<<<dim3(8192), dim3(256), 0, stream>>>(h, conv_w, conv_b, xc, lay, dil[lay]);
    lvc_kernel<<<dim3(512), dim3(512), 0, stream>>>(xc, kb, bbv, h, lay);
  }
}

// Round 3
// 707.322 us; speedup vs baseline: 4.5587x; 1.9705x over previous
//
#include <hip/hip_runtime.h>

#define TSZ 32768
#define LWN 98304

typedef float f32x4 __attribute__((ext_vector_type(4)));
typedef float f32x8 __attribute__((ext_vector_type(8)));
typedef short s16x8 __attribute__((ext_vector_type(8)));
typedef unsigned short u16x8 __attribute__((ext_vector_type(8)));

__device__ __forceinline__ float leaky(float x) { return x > 0.f ? x : 0.2f * x; }
__device__ __forceinline__ float bf2f(unsigned short b) { return __uint_as_float(((unsigned)b) << 16); }
__device__ __forceinline__ unsigned short f2bf(float f) {
  unsigned u = __float_as_uint(f);
  u += 0x7fffu + ((u >> 16) & 1u);
  return (unsigned short)(u >> 16);
}

// ---------------- conv_transpose: h = convT(leaky(x)) + ct_b -----------------
__global__ __launch_bounds__(256) void ct_kernel(const float* __restrict__ x,
                                                 const float* __restrict__ ct_w,
                                                 const float* __restrict__ ct_b,
                                                 float* __restrict__ h) {
  __shared__ float wl[2 * 64 * 64];
  __shared__ float xl[17 * 64];
  int bid = blockIdx.x;
  int qc = bid & 255, phi = (bid >> 8) & 7, b = bid >> 11;
  int w0 = (11 - phi) & 7;
  int d0 = (phi + w0 - 11) >> 3;  // -1 or 0
  int tid = threadIdx.x;
  for (int e = tid; e < 8192; e += 256) {
    int w2 = e >> 12, rest = e & 4095;
    wl[e] = ct_w[(w0 + 8 * w2) * 4096 + rest];
  }
  int mstart = qc * 16 + d0;
  for (int e = tid; e < 17 * 64; e += 256) {
    int mr = e >> 6, i = e & 63;
    int m = mstart + mr;
    xl[e] = (m >= 0 && m < 4096) ? leaky(x[((b << 12) + m) * 64 + i]) : 0.f;
  }
  __syncthreads();
  int o = tid & 63, tg4 = tid >> 6;
  float bv = ct_b[o];
  float acc[4] = {bv, bv, bv, bv};
  for (int w2 = 0; w2 < 2; w2++) {
    const float* wp = &wl[w2 * 4096];
    int rbase = tg4 * 4 + w2;
    const float* xp = &xl[rbase * 64];
    for (int i = 0; i < 64; i++) {
      float wv = wp[i * 64 + o];
      acc[0] += xp[i] * wv;
      acc[1] += xp[64 + i] * wv;
      acc[2] += xp[128 + i] * wv;
      acc[3] += xp[192 + i] * wv;
    }
  }
  for (int r = 0; r < 4; r++) {
    int t = (qc * 16 + tg4 * 4 + r) * 8 + phi;
    h[(((size_t)b << 15) + t) * 64 + o] = acc[r];
  }
}

// ---------------- conditioning network (tiny) -----------------
__global__ __launch_bounds__(256) void conv5_kernel(const float* __restrict__ c,
                                                    const float* __restrict__ w,
                                                    const float* __restrict__ bias,
                                                    float* __restrict__ cc) {
  int f = blockIdx.x * 256 + threadIdx.x;  // 32768
  int o = f & 63, t = (f >> 6) & 127, b = f >> 13;
  float acc = bias[o];
  for (int kk = 0; kk < 5; kk++) {
    int tt = t + kk - 2;
    if (tt < 0 || tt >= 128) continue;
    const float* cr = c + (b * 128 + tt) * 80;
    const float* wr = w + kk * 80 * 64 + o;
    for (int i = 0; i < 80; i++) acc += cr[i] * wr[i * 64];
  }
  cc[f] = leaky(acc);
}

template <int ADD>
__global__ __launch_bounds__(256) void conv3_kernel(const float* __restrict__ xin,
                                                    const float* __restrict__ w,
                                                    const float* __restrict__ bias,
                                                    const float* __restrict__ addsrc,
                                                    float* __restrict__ out) {
  int f = blockIdx.x * 256 + threadIdx.x;  // 32768
  int o = f & 63, t = (f >> 6) & 127, b = f >> 13;
  float acc = bias[o];
  for (int kk = 0; kk < 3; kk++) {
    int tt = t + kk - 1;
    if (tt < 0 || tt >= 128) continue;
    const float* xr = xin + (b * 128 + tt) * 64;
    const float* wr = w + kk * 64 * 64 + o;
    for (int i = 0; i < 64; i++) acc += xr[i] * wr[i * 64];
  }
  float v = leaky(acc);
  if (ADD) v += addsrc[f];
  out[f] = v;
}

// ---------------- im2col patches for the prediction GEMMs -----------------
__global__ __launch_bounds__(256) void patch_kernel(const float* __restrict__ cc,
                                                    float* __restrict__ A) {
  int f = blockIdx.x * 256 + threadIdx.x;  // 98304
  int k = f % 192, m = f / 192;
  int b = m >> 7, l = m & 127;
  int kk = k >> 6, hh = k & 63;
  int ll = l + kk - 1;
  A[f] = (ll >= 0 && ll < 128) ? cc[((b << 7) + ll) * 64 + hh] : 0.f;
}

__global__ __launch_bounds__(256) void bbgemm_kernel(const float* __restrict__ A,
                                                     const float* __restrict__ w,
                                                     const float* __restrict__ bias,
                                                     float* __restrict__ bb) {
  int f = blockIdx.x * 256 + threadIdx.x;  // 262144
  int n = f & 511, m = f >> 9;
  float acc = bias[n];
  const float* ar = A + m * 192;
  const float* wr = w + n;
  for (int k = 0; k < 192; k++) acc += ar[k] * wr[k * 512];
  bb[f] = acc;
}

// ---------------- pre-swizzle W and A into MFMA fragment layout (bf16) ----------
__global__ __launch_bounds__(256) void wreorg_kernel(const float* __restrict__ W,
                                                     unsigned short* __restrict__ Wf) {
  int ft = blockIdx.x * 256 + threadIdx.x;  // 2359296
  int lane = ft & 63, fragid = ft >> 6;
  int kf = fragid % 6, nt = fragid / 6;
  int col = lane & 15, q = lane >> 4;
  int n = nt * 16 + col;
  u16x8 v;
  for (int j = 0; j < 8; j++) {
    int kki = kf * 32 + q * 8 + j;
    v[j] = f2bf(W[(size_t)kki * LWN + n]);
  }
  *(u16x8*)(Wf + ((size_t)fragid * 64 + lane) * 8) = v;
}

__global__ __launch_bounds__(256) void afrag_kernel(const float* __restrict__ A,
                                                    unsigned short* __restrict__ Af) {
  int ft = blockIdx.x * 256 + threadIdx.x;  // 12288
  int lane = ft & 63, fragid = ft >> 6;
  int kf = fragid % 6, mt = fragid / 6;
  int row = lane & 15, q = lane >> 4;
  const float* ar = A + (mt * 16 + row) * 192 + kf * 32 + q * 8;
  u16x8 v;
  for (int j = 0; j < 8; j++) v[j] = f2bf(ar[j]);
  *(u16x8*)(Af + ((size_t)fragid * 64 + lane) * 8) = v;
}

// ---------------- dconv weights -> B-fragment layout (all 4 layers, built once) ----
// dwf[lay][(nt*6+kf)*512 + lane*8 + j] = bf16(conv_w[lay][kk][i][nt*16+(lane&15)])
//   with k = kf*32 + (lane>>4)*8 + j, kk=k>>6, i=k&63.
__global__ __launch_bounds__(256) void dwfrag_kernel(const float* __restrict__ conv_w,
                                                     unsigned short* __restrict__ dwf) {
  int ft = blockIdx.x * 256 + threadIdx.x;  // 6144
  int lane = ft & 63, frag = ft >> 6;       // 96 frags
  int lay = frag / 24, fr = frag % 24;
  int nt = fr / 6, kf = fr % 6;
  int o = nt * 16 + (lane & 15);
  int k0 = kf * 32 + (lane >> 4) * 8;
  u16x8 v;
  for (int j = 0; j < 8; j++) {
    int k = k0 + j, kk = k >> 6, i = k & 63;
    v[j] = f2bf(conv_w[lay * 12288 + kk * 4096 + i * 64 + o]);
  }
  *(u16x8*)(dwf + ((size_t)frag * 64 + lane) * 8) = v;
}

// ---------------- k = A @ W + kern_b  (M=512, N=98304, K=192), bf16 MFMA ----------
__global__ __launch_bounds__(256) void kgemm_kernel(const unsigned short* __restrict__ Af,
                                                    const unsigned short* __restrict__ Wf,
                                                    const float* __restrict__ kern_b,
                                                    unsigned short* __restrict__ kbf) {
  int wave = threadIdx.x >> 6, lane = threadIdx.x & 63;
  int col = lane & 15, q = lane >> 4;
  int mt0 = blockIdx.y * 16 + wave * 4;
  int nt0 = blockIdx.x * 4;
  f32x4 acc[4][4];
  for (int a = 0; a < 4; a++)
    for (int cg = 0; cg < 4; cg++) acc[a][cg] = (f32x4){0.f, 0.f, 0.f, 0.f};
  const s16x8* ap = (const s16x8*)Af;
  const s16x8* bp = (const s16x8*)Wf;
  for (int kf = 0; kf < 6; kf++) {
    s16x8 av[4], bv[4];
    for (int a = 0; a < 4; a++) av[a] = ap[((mt0 + a) * 6 + kf) * 64 + lane];
    for (int cg = 0; cg < 4; cg++) bv[cg] = bp[((size_t)(nt0 + cg) * 6 + kf) * 64 + lane];
    for (int a = 0; a < 4; a++)
      for (int cg = 0; cg < 4; cg++)
        acc[a][cg] = __builtin_amdgcn_mfma_f32_16x16x32_bf16(av[a], bv[cg], acc[a][cg], 0, 0, 0);
  }
  for (int cg = 0; cg < 4; cg++) {
    int n = (nt0 + cg) * 16 + col;
    float bias = kern_b[n];
    // decompose n -> (l2, i, o, kk) -> fragment coords
    int l2 = n / 24576;
    int rem = n - l2 * 24576;
    int i = rem / 384;
    int rem2 = rem - i * 384;
    int o = rem2 / 3;
    int kk = rem2 - o * 3;
    int k_idx = kk * 64 + i;
    int kf2 = k_idx >> 5, qq2 = (k_idx >> 3) & 3, j = k_idx & 7;
    int nt = o >> 4, lanec = qq2 * 16 + (o & 15);
    size_t fragoff = (size_t)(nt * 6 + kf2) * 512 + lanec * 8 + j;
    for (int a = 0; a < 4; a++) {
      int mbase = (mt0 + a) * 16 + q * 4;
      for (int r = 0; r < 4; r++) {
        int m = mbase + r;
        int bb_ = m >> 7, layl = m & 127;
        int lay = layl >> 5, lq = layl & 31;
        int l = lq * 4 + l2;
        size_t base = (size_t)((bb_ * 4 + lay) * 128 + l) * 24576;
        kbf[base + fragoff] = f2bf(acc[a][cg][r] + bias);
      }
    }
  }
}

// ---------------- dilated conv as MFMA GEMM: M=131072, N=64, K=192 ----------------
// xc = bf16(leaky(conv3_dil(leaky(h)))). A input = fp32 h, split on the fly into
// hi/lo bf16 pair (acc += hi*W + lo*W == fp32-input precision with bf16 weights).
// 512 blocks x 4 waves; wave = 64 rows x 64 cols; no LDS, no barriers.
__global__ __launch_bounds__(256) void dconv_kernel(const float* __restrict__ h,
                                                    const unsigned short* __restrict__ dwf,
                                                    const float* __restrict__ conv_b,
                                                    unsigned short* __restrict__ xc,
                                                    int lay, int d) {
  int tid = threadIdx.x;
  int w = tid >> 6, lane = tid & 63;
  int col = lane & 15, q = lane >> 4;
  int m0 = blockIdx.x * 256 + w * 64;
  int b = m0 >> 15, t0 = m0 & 32767;
  const float* hb = h + (((size_t)b) << 15) * 64;
  const s16x8* wf = (const s16x8*)(dwf + (size_t)lay * 24 * 512);

  f32x4 acc[4][4];
  for (int mt = 0; mt < 4; mt++)
    for (int cg = 0; cg < 4; cg++) acc[mt][cg] = (f32x4){0.f, 0.f, 0.f, 0.f};

#pragma unroll
  for (int kf = 0; kf < 6; kf++) {
    s16x8 bv[4];
#pragma unroll
    for (int cg = 0; cg < 4; cg++) bv[cg] = wf[(cg * 6 + kf) * 64 + lane];
    int k0 = kf * 32 + q * 8;
    int kk = k0 >> 6, i0 = k0 & 63;
    int dt = (kk - 1) * d;
    s16x8 ah[4], al[4];
#pragma unroll
    for (int mt = 0; mt < 4; mt++) {
      int t = t0 + mt * 16 + col + dt;
      bool oob = ((unsigned)t >= (unsigned)TSZ);
      int tc = oob ? 0 : t;
      f32x8 v = *(const f32x8*)(hb + (size_t)tc * 64 + i0);
#pragma unroll
      for (int j = 0; j < 8; j++) {
        float xv = oob ? 0.f : leaky(v[j]);
        unsigned short hi = f2bf(xv);
        ah[mt][j] = (short)hi;
        al[mt][j] = (short)f2bf(xv - bf2f(hi));
      }
    }
#pragma unroll
    for (int mt = 0; mt < 4; mt++)
#pragma unroll
      for (int cg = 0; cg < 4; cg++) {
        acc[mt][cg] = __builtin_amdgcn_mfma_f32_16x16x32_bf16(ah[mt], bv[cg], acc[mt][cg], 0, 0, 0);
        acc[mt][cg] = __builtin_amdgcn_mfma_f32_16x16x32_bf16(al[mt], bv[cg], acc[mt][cg], 0, 0, 0);
      }
  }

  unsigned short* xb = xc + (((size_t)b) << 15) * 64;
#pragma unroll
  for (int cg = 0; cg < 4; cg++) {
    int o = cg * 16 + col;
    float bias = conv_b[lay * 64 + o];
#pragma unroll
    for (int mt = 0; mt < 4; mt++)
#pragma unroll
      for (int r = 0; r < 4; r++) {
        int t = t0 + mt * 16 + q * 4 + r;
        xb[(size_t)t * 64 + o] = f2bf(leaky(acc[mt][cg][r] + bias));
      }
  }
}

// ---------------- LVC as per-(b,l) MFMA GEMM: M=256, N=128, K=192 ----------------
__global__ __launch_bounds__(512) void lvc_kernel(const unsigned short* __restrict__ xc,
                                                  const unsigned short* __restrict__ kbf,
                                                  const float* __restrict__ bbv,
                                                  float* __restrict__ h, int lay) {
  int tid = threadIdx.x;
  int l = blockIdx.x & 127, b = blockIdx.x >> 7;
  int w = tid >> 6, lane = tid & 63;
  int wm = w & 3, wn = w >> 2;
  int col = lane & 15, qq = lane >> 4;
  const s16x8* bbase = (const s16x8*)(kbf + (size_t)((b * 4 + lay) * 128 + l) * 24576);
  const unsigned short* xb = xc + (((size_t)b) << 15) * 64;

  f32x4 acc[4][4];
  for (int mt = 0; mt < 4; mt++)
    for (int cg = 0; cg < 4; cg++) acc[mt][cg] = (f32x4){0.f, 0.f, 0.f, 0.f};

  s16x8 av[2][4], bv[2][4];
  const s16x8 zfrag = {0, 0, 0, 0, 0, 0, 0, 0};

#define LOAD_STEP(p, kf)                                                            \
  {                                                                                 \
    int k0 = (kf) * 32 + qq * 8;                                                    \
    int kk = k0 >> 6, i0 = k0 & 63;                                                 \
    _Pragma("unroll") for (int mt = 0; mt < 4; mt++) {                              \
      int s = wm * 64 + mt * 16 + col;                                              \
      int nr = 3 * s + kk - 255;                                                    \
      int n = nr < 0 ? -nr : (nr >= 258 ? 514 - nr : nr);                           \
      int t = l * 256 + n - 1;                                                      \
      bool oob = ((unsigned)t >= (unsigned)TSZ);                                    \
      int tc = oob ? 0 : t;                                                         \
      s16x8 v = *(const s16x8*)(xb + (size_t)tc * 64 + i0);                         \
      av[p][mt] = oob ? zfrag : v;                                                  \
    }                                                                               \
    _Pragma("unroll") for (int cg = 0; cg < 4; cg++) {                              \
      int nt = 2 * wn + (cg & 1) + ((cg >> 1) << 2);                                \
      bv[p][cg] = bbase[(nt * 6 + (kf)) * 64 + lane];                               \
    }                                                                               \
  }

  LOAD_STEP(0, 0)
#pragma unroll
  for (int kf = 0; kf < 6; kf++) {
    int cur = kf & 1, nxt = cur ^ 1;
    if (kf < 5) LOAD_STEP(nxt, kf + 1)
#pragma unroll
    for (int mt = 0; mt < 4; mt++)
#pragma unroll
      for (int cg = 0; cg < 4; cg++)
        acc[mt][cg] =
            __builtin_amdgcn_mfma_f32_16x16x32_bf16(av[cur][mt], bv[cur][cg], acc[mt][cg], 0, 0, 0);
  }
#undef LOAD_STEP

  // epilogue: bias + sigmoid*tanh gate + h residual update
  int lq = l >> 2, l2 = l & 3;
  const float* bb0 = bbv + (size_t)(b * 128 + lay * 32 + lq) * 512 + l2 * 128;
  float* hb = h + ((((size_t)b) << 15) + l * 256) * 64;
#pragma unroll
  for (int mt = 0; mt < 4; mt++) {
#pragma unroll
    for (int p = 0; p < 2; p++) {
      int o = (2 * wn + p) * 16 + col;
      float b0 = bb0[o], b1 = bb0[o + 64];
#pragma unroll
      for (int r = 0; r < 4; r++) {
        int s = wm * 64 + mt * 16 + qq * 4 + r;
        float a0 = acc[mt][p][r] + b0;
        float a1 = acc[mt][p + 2][r] + b1;
        float sg = 1.f / (1.f + __expf(-a0));
        float ex = __expf(2.f * a1);
        float th = 1.f - 2.f / (ex + 1.f);
        hb[(size_t)s * 64 + o] += sg * th;
      }
    }
  }
}

extern "C" void kernel_launch(void* const* d_in, const int* in_sizes, int n_in,
                              void* d_out, int out_size, void* d_ws, size_t ws_size,
                              hipStream_t stream) {
  (void)in_sizes; (void)n_in; (void)out_size; (void)ws_size;
  const float* x      = (const float*)d_in[0];
  const float* c      = (const float*)d_in[1];
  const float* ct_w   = (const float*)d_in[2];
  const float* ct_b   = (const float*)d_in[3];
  const float* conv_w = (const float*)d_in[4];
  const float* conv_b = (const float*)d_in[5];
  const float* inp_w  = (const float*)d_in[6];
  const float* inp_b  = (const float*)d_in[7];
  const float* res_w1 = (const float*)d_in[8];
  const float* res_b1 = (const float*)d_in[9];
  const float* res_w2 = (const float*)d_in[10];
  const float* res_b2 = (const float*)d_in[11];
  const float* kern_w = (const float*)d_in[12];
  const float* kern_b = (const float*)d_in[13];
  const float* bias_w = (const float*)d_in[14];
  const float* bias_b = (const float*)d_in[15];

  float* h = (float*)d_out;  // h lives in d_out (fully written by ct_kernel)
  char* ws = (char*)d_ws;
  // region [0, 37748736): Wf during GEMM phase, then reused as bf16 xc in layer phase
  unsigned short* Wf = (unsigned short*)(ws);
  unsigned short* xc = (unsigned short*)(ws);
  unsigned short* kb = (unsigned short*)(ws + 37748736);   // 100663296 B (fragment layout)
  float* A           = (float*)(ws + 138412032);           // 393216 B
  unsigned short* Af = (unsigned short*)(ws + 138805248);  // 196608 B
  float* cc          = (float*)(ws + 139001856);           // 131072 B
  float* t1          = (float*)(ws + 139132928);           // 131072 B
  float* bbv         = (float*)(ws + 139264000);           // 1048576 B
  unsigned short* dwf = (unsigned short*)(ws + 140312576); // 98304 B

  ct_kernel<<<dim3(8192), dim3(256), 0, stream>>>(x, ct_w, ct_b, h);
  conv5_kernel<<<dim3(128), dim3(256), 0, stream>>>(c, inp_w, inp_b, cc);
  for (int j = 0; j < 3; j++) {
    conv3_kernel<0><<<dim3(128), dim3(256), 0, stream>>>(cc, res_w1 + j * 12288, res_b1 + j * 64,
                                                         (const float*)nullptr, t1);
    conv3_kernel<1><<<dim3(128), dim3(256), 0, stream>>>(t1, res_w2 + j * 12288, res_b2 + j * 64,
                                                         cc, cc);
  }
  patch_kernel<<<dim3(384), dim3(256), 0, stream>>>(cc, A);
  bbgemm_kernel<<<dim3(1024), dim3(256), 0, stream>>>(A, bias_w, bias_b, bbv);
  wreorg_kernel<<<dim3(9216), dim3(256), 0, stream>>>(kern_w, Wf);
  afrag_kernel<<<dim3(48), dim3(256), 0, stream>>>(A, Af);
  kgemm_kernel<<<dim3(1536, 2), dim3(256), 0, stream>>>(Af, Wf, kern_b, kb);
  dwfrag_kernel<<<dim3(24), dim3(256), 0, stream>>>(conv_w, dwf);

  const int dil[4] = {1, 3, 9, 27};
  for (int lay = 0; lay < 4; lay++) {
    dconv_kernel<<<dim3(512), dim3(256), 0, stream>>>(h, dwf, conv_b, xc, lay, dil[lay]);
    lvc_kernel<<<dim3(512), dim3(512), 0, stream>>>(xc, kb, bbv, h, lay);
  }
}

// Round 4
// 637.641 us; speedup vs baseline: 5.0569x; 1.1093x over previous
//
#include <hip/hip_runtime.h>

#define TSZ 32768
#define LWN 98304

typedef float f32x4 __attribute__((ext_vector_type(4)));
typedef float f32x8 __attribute__((ext_vector_type(8)));
typedef short s16x8 __attribute__((ext_vector_type(8)));
typedef unsigned short u16x8 __attribute__((ext_vector_type(8)));

__device__ __forceinline__ float leaky(float x) { return x > 0.f ? x : 0.2f * x; }
__device__ __forceinline__ float bf2f(unsigned short b) { return __uint_as_float(((unsigned)b) << 16); }
__device__ __forceinline__ unsigned short f2bf(float f) {
  unsigned u = __float_as_uint(f);
  u += 0x7fffu + ((u >> 16) & 1u);
  return (unsigned short)(u >> 16);
}

// ---------------- conv_transpose: h = convT(leaky(x)) + ct_b -----------------
__global__ __launch_bounds__(256) void ct_kernel(const float* __restrict__ x,
                                                 const float* __restrict__ ct_w,
                                                 const float* __restrict__ ct_b,
                                                 float* __restrict__ h) {
  __shared__ float wl[2 * 64 * 64];
  __shared__ float xl[17 * 64];
  int bid = blockIdx.x;
  int qc = bid & 255, phi = (bid >> 8) & 7, b = bid >> 11;
  int w0 = (11 - phi) & 7;
  int d0 = (phi + w0 - 11) >> 3;  // -1 or 0
  int tid = threadIdx.x;
  for (int e = tid; e < 8192; e += 256) {
    int w2 = e >> 12, rest = e & 4095;
    wl[e] = ct_w[(w0 + 8 * w2) * 4096 + rest];
  }
  int mstart = qc * 16 + d0;
  for (int e = tid; e < 17 * 64; e += 256) {
    int mr = e >> 6, i = e & 63;
    int m = mstart + mr;
    xl[e] = (m >= 0 && m < 4096) ? leaky(x[((b << 12) + m) * 64 + i]) : 0.f;
  }
  __syncthreads();
  int o = tid & 63, tg4 = tid >> 6;
  float bv = ct_b[o];
  float acc[4] = {bv, bv, bv, bv};
  for (int w2 = 0; w2 < 2; w2++) {
    const float* wp = &wl[w2 * 4096];
    int rbase = tg4 * 4 + w2;
    const float* xp = &xl[rbase * 64];
    for (int i = 0; i < 64; i++) {
      float wv = wp[i * 64 + o];
      acc[0] += xp[i] * wv;
      acc[1] += xp[64 + i] * wv;
      acc[2] += xp[128 + i] * wv;
      acc[3] += xp[192 + i] * wv;
    }
  }
  for (int r = 0; r < 4; r++) {
    int t = (qc * 16 + tg4 * 4 + r) * 8 + phi;
    h[(((size_t)b << 15) + t) * 64 + o] = acc[r];
  }
}

// ---------------- conditioning network (tiny) -----------------
__global__ __launch_bounds__(256) void conv5_kernel(const float* __restrict__ c,
                                                    const float* __restrict__ w,
                                                    const float* __restrict__ bias,
                                                    float* __restrict__ cc) {
  int f = blockIdx.x * 256 + threadIdx.x;  // 32768
  int o = f & 63, t = (f >> 6) & 127, b = f >> 13;
  float acc = bias[o];
  for (int kk = 0; kk < 5; kk++) {
    int tt = t + kk - 2;
    if (tt < 0 || tt >= 128) continue;
    const float* cr = c + (b * 128 + tt) * 80;
    const float* wr = w + kk * 80 * 64 + o;
    for (int i = 0; i < 80; i++) acc += cr[i] * wr[i * 64];
  }
  cc[f] = leaky(acc);
}

template <int ADD>
__global__ __launch_bounds__(256) void conv3_kernel(const float* __restrict__ xin,
                                                    const float* __restrict__ w,
                                                    const float* __restrict__ bias,
                                                    const float* __restrict__ addsrc,
                                                    float* __restrict__ out) {
  int f = blockIdx.x * 256 + threadIdx.x;  // 32768
  int o = f & 63, t = (f >> 6) & 127, b = f >> 13;
  float acc = bias[o];
  for (int kk = 0; kk < 3; kk++) {
    int tt = t + kk - 1;
    if (tt < 0 || tt >= 128) continue;
    const float* xr = xin + (b * 128 + tt) * 64;
    const float* wr = w + kk * 64 * 64 + o;
    for (int i = 0; i < 64; i++) acc += xr[i] * wr[i * 64];
  }
  float v = leaky(acc);
  if (ADD) v += addsrc[f];
  out[f] = v;
}

// ---------------- im2col patches for the prediction GEMMs -----------------
__global__ __launch_bounds__(256) void patch_kernel(const float* __restrict__ cc,
                                                    float* __restrict__ A) {
  int f = blockIdx.x * 256 + threadIdx.x;  // 98304
  int k = f % 192, m = f / 192;
  int b = m >> 7, l = m & 127;
  int kk = k >> 6, hh = k & 63;
  int ll = l + kk - 1;
  A[f] = (ll >= 0 && ll < 128) ? cc[((b << 7) + ll) * 64 + hh] : 0.f;
}

__global__ __launch_bounds__(256) void bbgemm_kernel(const float* __restrict__ A,
                                                     const float* __restrict__ w,
                                                     const float* __restrict__ bias,
                                                     float* __restrict__ bb) {
  int f = blockIdx.x * 256 + threadIdx.x;  // 262144
  int n = f & 511, m = f >> 9;
  float acc = bias[n];
  const float* ar = A + m * 192;
  const float* wr = w + n;
  for (int k = 0; k < 192; k++) acc += ar[k] * wr[k * 512];
  bb[f] = acc;
}

// ---------------- pre-swizzle W and A into MFMA fragment layout (bf16) ----------
__global__ __launch_bounds__(256) void wreorg_kernel(const float* __restrict__ W,
                                                     unsigned short* __restrict__ Wf) {
  int ft = blockIdx.x * 256 + threadIdx.x;  // 2359296
  int lane = ft & 63, fragid = ft >> 6;
  int kf = fragid % 6, nt = fragid / 6;
  int col = lane & 15, q = lane >> 4;
  int n = nt * 16 + col;
  u16x8 v;
  for (int j = 0; j < 8; j++) {
    int kki = kf * 32 + q * 8 + j;
    v[j] = f2bf(W[(size_t)kki * LWN + n]);
  }
  *(u16x8*)(Wf + ((size_t)fragid * 64 + lane) * 8) = v;
}

__global__ __launch_bounds__(256) void afrag_kernel(const float* __restrict__ A,
                                                    unsigned short* __restrict__ Af) {
  int ft = blockIdx.x * 256 + threadIdx.x;  // 12288
  int lane = ft & 63, fragid = ft >> 6;
  int kf = fragid % 6, mt = fragid / 6;
  int row = lane & 15, q = lane >> 4;
  const float* ar = A + (mt * 16 + row) * 192 + kf * 32 + q * 8;
  u16x8 v;
  for (int j = 0; j < 8; j++) v[j] = f2bf(ar[j]);
  *(u16x8*)(Af + ((size_t)fragid * 64 + lane) * 8) = v;
}

// ---------------- dconv weights -> B-fragment layout (all 4 layers, built once) ----
__global__ __launch_bounds__(256) void dwfrag_kernel(const float* __restrict__ conv_w,
                                                     unsigned short* __restrict__ dwf) {
  int ft = blockIdx.x * 256 + threadIdx.x;  // 6144
  int lane = ft & 63, frag = ft >> 6;       // 96 frags
  int lay = frag / 24, fr = frag % 24;
  int nt = fr / 6, kf = fr % 6;
  int o = nt * 16 + (lane & 15);
  int k0 = kf * 32 + (lane >> 4) * 8;
  u16x8 v;
  for (int j = 0; j < 8; j++) {
    int k = k0 + j, kk = k >> 6, i = k & 63;
    v[j] = f2bf(conv_w[lay * 12288 + kk * 4096 + i * 64 + o]);
  }
  *(u16x8*)(dwf + ((size_t)frag * 64 + lane) * 8) = v;
}

// ---------------- k = A @ W + kern_b  (M=512, N=98304, K=192), bf16 MFMA ----------
// Plain row-major bf16 output kbs[m*98304+n]: lanes 0-15 cover consecutive n
// (32B segments), cg loop covers n 0..63 within the same rows -> L2 merges to
// full lines (write amplification ~1, vs 8.4x with the fragment-scatter store).
__global__ __launch_bounds__(256) void kgemm_kernel(const unsigned short* __restrict__ Af,
                                                    const unsigned short* __restrict__ Wf,
                                                    const float* __restrict__ kern_b,
                                                    unsigned short* __restrict__ kbs) {
  int wave = threadIdx.x >> 6, lane = threadIdx.x & 63;
  int col = lane & 15, q = lane >> 4;
  int mt0 = blockIdx.y * 16 + wave * 4;
  int nt0 = blockIdx.x * 4;
  f32x4 acc[4][4];
  for (int a = 0; a < 4; a++)
    for (int cg = 0; cg < 4; cg++) acc[a][cg] = (f32x4){0.f, 0.f, 0.f, 0.f};
  const s16x8* ap = (const s16x8*)Af;
  const s16x8* bp = (const s16x8*)Wf;
  for (int kf = 0; kf < 6; kf++) {
    s16x8 av[4], bv[4];
    for (int a = 0; a < 4; a++) av[a] = ap[((mt0 + a) * 6 + kf) * 64 + lane];
    for (int cg = 0; cg < 4; cg++) bv[cg] = bp[((size_t)(nt0 + cg) * 6 + kf) * 64 + lane];
    for (int a = 0; a < 4; a++)
      for (int cg = 0; cg < 4; cg++)
        acc[a][cg] = __builtin_amdgcn_mfma_f32_16x16x32_bf16(av[a], bv[cg], acc[a][cg], 0, 0, 0);
  }
  for (int cg = 0; cg < 4; cg++) {
    int n = (nt0 + cg) * 16 + col;
    float bias = kern_b[n];
    for (int a = 0; a < 4; a++) {
      int mbase = (mt0 + a) * 16 + q * 4;
      for (int r = 0; r < 4; r++)
        kbs[(size_t)(mbase + r) * LWN + n] = f2bf(acc[a][cg][r] + bias);
    }
  }
}

// ---------------- dilated conv as MFMA GEMM: M=131072, N=64, K=192 ----------------
__global__ __launch_bounds__(256) void dconv_kernel(const float* __restrict__ h,
                                                    const unsigned short* __restrict__ dwf,
                                                    const float* __restrict__ conv_b,
                                                    unsigned short* __restrict__ xc,
                                                    int lay, int d) {
  int tid = threadIdx.x;
  int w = tid >> 6, lane = tid & 63;
  int col = lane & 15, q = lane >> 4;
  int m0 = blockIdx.x * 256 + w * 64;
  int b = m0 >> 15, t0 = m0 & 32767;
  const float* hb = h + (((size_t)b) << 15) * 64;
  const s16x8* wf = (const s16x8*)(dwf + (size_t)lay * 24 * 512);

  f32x4 acc[4][4];
  for (int mt = 0; mt < 4; mt++)
    for (int cg = 0; cg < 4; cg++) acc[mt][cg] = (f32x4){0.f, 0.f, 0.f, 0.f};

#pragma unroll
  for (int kf = 0; kf < 6; kf++) {
    s16x8 bv[4];
#pragma unroll
    for (int cg = 0; cg < 4; cg++) bv[cg] = wf[(cg * 6 + kf) * 64 + lane];
    int k0 = kf * 32 + q * 8;
    int kk = k0 >> 6, i0 = k0 & 63;
    int dt = (kk - 1) * d;
    s16x8 ah[4], al[4];
#pragma unroll
    for (int mt = 0; mt < 4; mt++) {
      int t = t0 + mt * 16 + col + dt;
      bool oob = ((unsigned)t >= (unsigned)TSZ);
      int tc = oob ? 0 : t;
      f32x8 v = *(const f32x8*)(hb + (size_t)tc * 64 + i0);
#pragma unroll
      for (int j = 0; j < 8; j++) {
        float xv = oob ? 0.f : leaky(v[j]);
        unsigned short hi = f2bf(xv);
        ah[mt][j] = (short)hi;
        al[mt][j] = (short)f2bf(xv - bf2f(hi));
      }
    }
#pragma unroll
    for (int mt = 0; mt < 4; mt++)
#pragma unroll
      for (int cg = 0; cg < 4; cg++) {
        acc[mt][cg] = __builtin_amdgcn_mfma_f32_16x16x32_bf16(ah[mt], bv[cg], acc[mt][cg], 0, 0, 0);
        acc[mt][cg] = __builtin_amdgcn_mfma_f32_16x16x32_bf16(al[mt], bv[cg], acc[mt][cg], 0, 0, 0);
      }
  }

  unsigned short* xb = xc + (((size_t)b) << 15) * 64;
#pragma unroll
  for (int cg = 0; cg < 4; cg++) {
    int o = cg * 16 + col;
    float bias = conv_b[lay * 64 + o];
#pragma unroll
    for (int mt = 0; mt < 4; mt++)
#pragma unroll
      for (int r = 0; r < 4; r++) {
        int t = t0 + mt * 16 + q * 4 + r;
        xb[(size_t)t * 64 + o] = f2bf(leaky(acc[mt][cg][r] + bias));
      }
  }
}

// ---------------- LVC as per-(b,l) MFMA GEMM: M=256, N=128, K=192 ----------------
// B-operand gathered from plain row-major kbs: slice = contiguous 48KB run of one
// row (read exactly once, amplification 1). Per fragment: 8 x 2B loads at stride
// 384 elems, e = i*384 + o*3 + kk (round-1-verified mapping).
__global__ __launch_bounds__(512) void lvc_kernel(const unsigned short* __restrict__ xc,
                                                  const unsigned short* __restrict__ kbs,
                                                  const float* __restrict__ bbv,
                                                  float* __restrict__ h, int lay) {
  int tid = threadIdx.x;
  int l = blockIdx.x & 127, b = blockIdx.x >> 7;
  int w = tid >> 6, lane = tid & 63;
  int wm = w & 3, wn = w >> 2;
  int col = lane & 15, qq = lane >> 4;
  const unsigned short* srow =
      kbs + (size_t)(b * 128 + lay * 32 + (l >> 2)) * LWN + (l & 3) * 24576;
  const unsigned short* xb = xc + (((size_t)b) << 15) * 64;

  f32x4 acc[4][4];
  for (int mt = 0; mt < 4; mt++)
    for (int cg = 0; cg < 4; cg++) acc[mt][cg] = (f32x4){0.f, 0.f, 0.f, 0.f};

  s16x8 av[2][4], bv[2][4];
  const s16x8 zfrag = {0, 0, 0, 0, 0, 0, 0, 0};

#define LOAD_STEP(p, kf)                                                            \
  {                                                                                 \
    int k0 = (kf) * 32 + qq * 8;                                                    \
    int kk = k0 >> 6, i0 = k0 & 63;                                                 \
    _Pragma("unroll") for (int mt = 0; mt < 4; mt++) {                              \
      int s = wm * 64 + mt * 16 + col;                                              \
      int nr = 3 * s + kk - 255;                                                    \
      int n = nr < 0 ? -nr : (nr >= 258 ? 514 - nr : nr);                           \
      int t = l * 256 + n - 1;                                                      \
      bool oob = ((unsigned)t >= (unsigned)TSZ);                                    \
      int tc = oob ? 0 : t;                                                         \
      s16x8 v = *(const s16x8*)(xb + (size_t)tc * 64 + i0);                         \
      av[p][mt] = oob ? zfrag : v;                                                  \
    }                                                                               \
    _Pragma("unroll") for (int cg = 0; cg < 4; cg++) {                              \
      int nt = 2 * wn + (cg & 1) + ((cg >> 1) << 2);                                \
      int o = nt * 16 + col;                                                        \
      const unsigned short* bp = srow + i0 * 384 + o * 3 + kk;                      \
      s16x8 bvv;                                                                    \
      _Pragma("unroll") for (int j = 0; j < 8; j++) bvv[j] = (short)bp[j * 384];    \
      bv[p][cg] = bvv;                                                              \
    }                                                                               \
  }

  LOAD_STEP(0, 0)
#pragma unroll
  for (int kf = 0; kf < 6; kf++) {
    int cur = kf & 1, nxt = cur ^ 1;
    if (kf < 5) LOAD_STEP(nxt, kf + 1)
#pragma unroll
    for (int mt = 0; mt < 4; mt++)
#pragma unroll
      for (int cg = 0; cg < 4; cg++)
        acc[mt][cg] =
            __builtin_amdgcn_mfma_f32_16x16x32_bf16(av[cur][mt], bv[cur][cg], acc[mt][cg], 0, 0, 0);
  }
#undef LOAD_STEP

  // epilogue: bias + sigmoid*tanh gate + h residual update
  int lq = l >> 2, l2 = l & 3;
  const float* bb0 = bbv + (size_t)(b * 128 + lay * 32 + lq) * 512 + l2 * 128;
  float* hb = h + ((((size_t)b) << 15) + l * 256) * 64;
#pragma unroll
  for (int mt = 0; mt < 4; mt++) {
#pragma unroll
    for (int p = 0; p < 2; p++) {
      int o = (2 * wn + p) * 16 + col;
      float b0 = bb0[o], b1 = bb0[o + 64];
#pragma unroll
      for (int r = 0; r < 4; r++) {
        int s = wm * 64 + mt * 16 + qq * 4 + r;
        float a0 = acc[mt][p][r] + b0;
        float a1 = acc[mt][p + 2][r] + b1;
        float sg = 1.f / (1.f + __expf(-a0));
        float ex = __expf(2.f * a1);
        float th = 1.f - 2.f / (ex + 1.f);
        hb[(size_t)s * 64 + o] += sg * th;
      }
    }
  }
}

extern "C" void kernel_launch(void* const* d_in, const int* in_sizes, int n_in,
                              void* d_out, int out_size, void* d_ws, size_t ws_size,
                              hipStream_t stream) {
  (void)in_sizes; (void)n_in; (void)out_size; (void)ws_size;
  const float* x      = (const float*)d_in[0];
  const float* c      = (const float*)d_in[1];
  const float* ct_w   = (const float*)d_in[2];
  const float* ct_b   = (const float*)d_in[3];
  const float* conv_w = (const float*)d_in[4];
  const float* conv_b = (const float*)d_in[5];
  const float* inp_w  = (const float*)d_in[6];
  const float* inp_b  = (const float*)d_in[7];
  const float* res_w1 = (const float*)d_in[8];
  const float* res_b1 = (const float*)d_in[9];
  const float* res_w2 = (const float*)d_in[10];
  const float* res_b2 = (const float*)d_in[11];
  const float* kern_w = (const float*)d_in[12];
  const float* kern_b = (const float*)d_in[13];
  const float* bias_w = (const float*)d_in[14];
  const float* bias_b = (const float*)d_in[15];

  float* h = (float*)d_out;  // h lives in d_out (fully written by ct_kernel)
  char* ws = (char*)d_ws;
  // region [0, 37748736): Wf during GEMM phase, then reused as bf16 xc in layer phase
  unsigned short* Wf = (unsigned short*)(ws);
  unsigned short* xc = (unsigned short*)(ws);
  unsigned short* kb = (unsigned short*)(ws + 37748736);   // 100663296 B (row-major [m][n] bf16)
  float* A           = (float*)(ws + 138412032);           // 393216 B
  unsigned short* Af = (unsigned short*)(ws + 138805248);  // 196608 B
  float* cc          = (float*)(ws + 139001856);           // 131072 B
  float* t1          = (float*)(ws + 139132928);           // 131072 B
  float* bbv         = (float*)(ws + 139264000);           // 1048576 B
  unsigned short* dwf = (unsigned short*)(ws + 140312576); // 98304 B

  ct_kernel<<<dim3(8192), dim3(256), 0, stream>>>(x, ct_w, ct_b, h);
  conv5_kernel<<<dim3(128), dim3(256), 0, stream>>>(c, inp_w, inp_b, cc);
  for (int j = 0; j < 3; j++) {
    conv3_kernel<0><<<dim3(128), dim3(256), 0, stream>>>(cc, res_w1 + j * 12288, res_b1 + j * 64,
                                                         (const float*)nullptr, t1);
    conv3_kernel<1><<<dim3(128), dim3(256), 0, stream>>>(t1, res_w2 + j * 12288, res_b2 + j * 64,
                                                         cc, cc);
  }
  patch_kernel<<<dim3(384), dim3(256), 0, stream>>>(cc, A);
  bbgemm_kernel<<<dim3(1024), dim3(256), 0, stream>>>(A, bias_w, bias_b, bbv);
  wreorg_kernel<<<dim3(9216), dim3(256), 0, stream>>>(kern_w, Wf);
  afrag_kernel<<<dim3(48), dim3(256), 0, stream>>>(A, Af);
  kgemm_kernel<<<dim3(1536, 2), dim3(256), 0, stream>>>(Af, Wf, kern_b, kb);
  dwfrag_kernel<<<dim3(24), dim3(256), 0, stream>>>(conv_w, dwf);

  const int dil[4] = {1, 3, 9, 27};
  for (int lay = 0; lay < 4; lay++) {
    dconv_kernel<<<dim3(512), dim3(256), 0, stream>>>(h, dwf, conv_b, xc, lay, dil[lay]);
    lvc_kernel<<<dim3(512), dim3(512), 0, stream>>>(xc, kb, bbv, h, lay);
  }
}

// Round 5
// 565.245 us; speedup vs baseline: 5.7046x; 1.1281x over previous
//
#include <hip/hip_runtime.h>

#define TSZ 32768
#define LWN 98304

typedef float f32x4 __attribute__((ext_vector_type(4)));
typedef float f32x8 __attribute__((ext_vector_type(8)));
typedef short s16x8 __attribute__((ext_vector_type(8)));
typedef unsigned short u16x8 __attribute__((ext_vector_type(8)));

__device__ __forceinline__ float leaky(float x) { return x > 0.f ? x : 0.2f * x; }
__device__ __forceinline__ float bf2f(unsigned short b) { return __uint_as_float(((unsigned)b) << 16); }
__device__ __forceinline__ unsigned short f2bf(float f) {
  unsigned u = __float_as_uint(f);
  u += 0x7fffu + ((u >> 16) & 1u);
  return (unsigned short)(u >> 16);
}

// ---------------- ct weights -> hi/lo B-fragment pairs (per phase) ----------------
// frag id = (phi*4 + nt)*4 + kf; element [lane*8+j]: k=kf*32+(lane>>4)*8+j,
// w2=k>>6, i=k&63, o=nt*16+(lane&15); src = ct_w[(w0+8*w2)*4096 + i*64 + o].
// hi frags at [0,128), lo frags at [128,256).
__global__ __launch_bounds__(256) void ctwfrag_kernel(const float* __restrict__ ct_w,
                                                      unsigned short* __restrict__ ctwf) {
  int ft = blockIdx.x * 256 + threadIdx.x;  // 8192
  int lane = ft & 63, frag = ft >> 6;       // 128 frags
  int phi = frag >> 4, fr = frag & 15;
  int nt = fr >> 2, kf = fr & 3;
  int w0 = (11 - phi) & 7;
  int o = nt * 16 + (lane & 15);
  int k0 = kf * 32 + (lane >> 4) * 8;
  u16x8 vh, vl;
  for (int j = 0; j < 8; j++) {
    int k = k0 + j, w2 = k >> 6, i = k & 63;
    float wv = ct_w[(w0 + 8 * w2) * 4096 + i * 64 + o];
    unsigned short hi = f2bf(wv);
    vh[j] = hi;
    vl[j] = f2bf(wv - bf2f(hi));
  }
  *(u16x8*)(ctwf + ((size_t)frag * 64 + lane) * 8) = vh;
  *(u16x8*)(ctwf + ((size_t)(frag + 128) * 64 + lane) * 8) = vl;
}

// ---------------- conv_transpose as MFMA GEMM (per phase): M=4096/b, N=64, K=128 ---
// A = leaky(x) split hi/lo on the fly; 3 products (ah*bh + al*bh + ah*bl) ~= fp32.
__global__ __launch_bounds__(256) void ctm_kernel(const float* __restrict__ x,
                                                  const unsigned short* __restrict__ ctwf,
                                                  const float* __restrict__ ct_b,
                                                  float* __restrict__ h) {
  int tid = threadIdx.x;
  int w = tid >> 6, lane = tid & 63;
  int col = lane & 15, q = lane >> 4;
  int bid = blockIdx.x;  // 512
  int blk = bid & 15, phi = (bid >> 4) & 7, b = bid >> 7;
  int w0 = (11 - phi) & 7;
  int d0 = (phi + w0 - 11) >> 3;  // -1 or 0
  int mm0 = blk * 256 + w * 64;
  const float* xb = x + (((size_t)b) << 12) * 64;
  const s16x8* wf = (const s16x8*)ctwf;

  f32x4 acc[4][4];
  for (int mt = 0; mt < 4; mt++)
    for (int cg = 0; cg < 4; cg++) acc[mt][cg] = (f32x4){0.f, 0.f, 0.f, 0.f};

#pragma unroll
  for (int kf = 0; kf < 4; kf++) {
    s16x8 bh[4], bl[4];
#pragma unroll
    for (int cg = 0; cg < 4; cg++) {
      int frag = (phi * 4 + cg) * 4 + kf;
      bh[cg] = wf[frag * 64 + lane];
      bl[cg] = wf[(frag + 128) * 64 + lane];
    }
    int k0 = kf * 32 + q * 8;
    int w2 = k0 >> 6, i0 = k0 & 63;
    int rb = mm0 + d0 + w2;
    s16x8 ah[4], al[4];
#pragma unroll
    for (int mt = 0; mt < 4; mt++) {
      int r = rb + mt * 16 + col;
      bool oob = ((unsigned)r >= 4096u);
      int rc = oob ? 0 : r;
      f32x8 v = *(const f32x8*)(xb + (size_t)rc * 64 + i0);
#pragma unroll
      for (int j = 0; j < 8; j++) {
        float xv = oob ? 0.f : leaky(v[j]);
        unsigned short hi = f2bf(xv);
        ah[mt][j] = (short)hi;
        al[mt][j] = (short)f2bf(xv - bf2f(hi));
      }
    }
#pragma unroll
    for (int mt = 0; mt < 4; mt++)
#pragma unroll
      for (int cg = 0; cg < 4; cg++) {
        acc[mt][cg] = __builtin_amdgcn_mfma_f32_16x16x32_bf16(ah[mt], bh[cg], acc[mt][cg], 0, 0, 0);
        acc[mt][cg] = __builtin_amdgcn_mfma_f32_16x16x32_bf16(al[mt], bh[cg], acc[mt][cg], 0, 0, 0);
        acc[mt][cg] = __builtin_amdgcn_mfma_f32_16x16x32_bf16(ah[mt], bl[cg], acc[mt][cg], 0, 0, 0);
      }
  }

  float* hb = h + (((size_t)b) << 15) * 64;
#pragma unroll
  for (int cg = 0; cg < 4; cg++) {
    int o = cg * 16 + col;
    float bias = ct_b[o];
#pragma unroll
    for (int mt = 0; mt < 4; mt++)
#pragma unroll
      for (int r = 0; r < 4; r++) {
        int mm = mm0 + mt * 16 + q * 4 + r;
        int t = mm * 8 + phi;
        hb[(size_t)t * 64 + o] = acc[mt][cg][r] + bias;
      }
  }
}

// ---------------- conditioning network (tiny) -----------------
__global__ __launch_bounds__(256) void conv5_kernel(const float* __restrict__ c,
                                                    const float* __restrict__ w,
                                                    const float* __restrict__ bias,
                                                    float* __restrict__ cc) {
  int f = blockIdx.x * 256 + threadIdx.x;  // 32768
  int o = f & 63, t = (f >> 6) & 127, b = f >> 13;
  float acc = bias[o];
  for (int kk = 0; kk < 5; kk++) {
    int tt = t + kk - 2;
    if (tt < 0 || tt >= 128) continue;
    const float* cr = c + (b * 128 + tt) * 80;
    const float* wr = w + kk * 80 * 64 + o;
    for (int i = 0; i < 80; i++) acc += cr[i] * wr[i * 64];
  }
  cc[f] = leaky(acc);
}

template <int ADD>
__global__ __launch_bounds__(256) void conv3_kernel(const float* __restrict__ xin,
                                                    const float* __restrict__ w,
                                                    const float* __restrict__ bias,
                                                    const float* __restrict__ addsrc,
                                                    float* __restrict__ out) {
  int f = blockIdx.x * 256 + threadIdx.x;  // 32768
  int o = f & 63, t = (f >> 6) & 127, b = f >> 13;
  float acc = bias[o];
  for (int kk = 0; kk < 3; kk++) {
    int tt = t + kk - 1;
    if (tt < 0 || tt >= 128) continue;
    const float* xr = xin + (b * 128 + tt) * 64;
    const float* wr = w + kk * 64 * 64 + o;
    for (int i = 0; i < 64; i++) acc += xr[i] * wr[i * 64];
  }
  float v = leaky(acc);
  if (ADD) v += addsrc[f];
  out[f] = v;
}

// ---------------- im2col patches for the prediction GEMMs -----------------
__global__ __launch_bounds__(256) void patch_kernel(const float* __restrict__ cc,
                                                    float* __restrict__ A) {
  int f = blockIdx.x * 256 + threadIdx.x;  // 98304
  int k = f % 192, m = f / 192;
  int b = m >> 7, l = m & 127;
  int kk = k >> 6, hh = k & 63;
  int ll = l + kk - 1;
  A[f] = (ll >= 0 && ll < 128) ? cc[((b << 7) + ll) * 64 + hh] : 0.f;
}

__global__ __launch_bounds__(256) void bbgemm_kernel(const float* __restrict__ A,
                                                     const float* __restrict__ w,
                                                     const float* __restrict__ bias,
                                                     float* __restrict__ bb) {
  int f = blockIdx.x * 256 + threadIdx.x;  // 262144
  int n = f & 511, m = f >> 9;
  float acc = bias[n];
  const float* ar = A + m * 192;
  const float* wr = w + n;
  for (int k = 0; k < 192; k++) acc += ar[k] * wr[k * 512];
  bb[f] = acc;
}

// ---------------- pre-swizzle W and A into MFMA fragment layout (bf16) ----------
__global__ __launch_bounds__(256) void wreorg_kernel(const float* __restrict__ W,
                                                     unsigned short* __restrict__ Wf) {
  int ft = blockIdx.x * 256 + threadIdx.x;  // 2359296
  int lane = ft & 63, fragid = ft >> 6;
  int kf = fragid % 6, nt = fragid / 6;
  int col = lane & 15, q = lane >> 4;
  int n = nt * 16 + col;
  u16x8 v;
  for (int j = 0; j < 8; j++) {
    int kki = kf * 32 + q * 8 + j;
    v[j] = f2bf(W[(size_t)kki * LWN + n]);
  }
  *(u16x8*)(Wf + ((size_t)fragid * 64 + lane) * 8) = v;
}

__global__ __launch_bounds__(256) void afrag_kernel(const float* __restrict__ A,
                                                    unsigned short* __restrict__ Af) {
  int ft = blockIdx.x * 256 + threadIdx.x;  // 12288
  int lane = ft & 63, fragid = ft >> 6;
  int kf = fragid % 6, mt = fragid / 6;
  int row = lane & 15, q = lane >> 4;
  const float* ar = A + (mt * 16 + row) * 192 + kf * 32 + q * 8;
  u16x8 v;
  for (int j = 0; j < 8; j++) v[j] = f2bf(ar[j]);
  *(u16x8*)(Af + ((size_t)fragid * 64 + lane) * 8) = v;
}

// ---------------- dconv weights -> B-fragment layout (all 4 layers, built once) ----
__global__ __launch_bounds__(256) void dwfrag_kernel(const float* __restrict__ conv_w,
                                                     unsigned short* __restrict__ dwf) {
  int ft = blockIdx.x * 256 + threadIdx.x;  // 6144
  int lane = ft & 63, frag = ft >> 6;       // 96 frags
  int lay = frag / 24, fr = frag % 24;
  int nt = fr / 6, kf = fr % 6;
  int o = nt * 16 + (lane & 15);
  int k0 = kf * 32 + (lane >> 4) * 8;
  u16x8 v;
  for (int j = 0; j < 8; j++) {
    int k = k0 + j, kk = k >> 6, i = k & 63;
    v[j] = f2bf(conv_w[lay * 12288 + kk * 4096 + i * 64 + o]);
  }
  *(u16x8*)(dwf + ((size_t)frag * 64 + lane) * 8) = v;
}

// ---------------- k = A @ W + kern_b  (M=512, N=98304, K=192), bf16 MFMA ----------
__global__ __launch_bounds__(256) void kgemm_kernel(const unsigned short* __restrict__ Af,
                                                    const unsigned short* __restrict__ Wf,
                                                    const float* __restrict__ kern_b,
                                                    unsigned short* __restrict__ kbs) {
  int wave = threadIdx.x >> 6, lane = threadIdx.x & 63;
  int col = lane & 15, q = lane >> 4;
  int mt0 = blockIdx.y * 16 + wave * 4;
  int nt0 = blockIdx.x * 4;
  f32x4 acc[4][4];
  for (int a = 0; a < 4; a++)
    for (int cg = 0; cg < 4; cg++) acc[a][cg] = (f32x4){0.f, 0.f, 0.f, 0.f};
  const s16x8* ap = (const s16x8*)Af;
  const s16x8* bp = (const s16x8*)Wf;
  for (int kf = 0; kf < 6; kf++) {
    s16x8 av[4], bv[4];
    for (int a = 0; a < 4; a++) av[a] = ap[((mt0 + a) * 6 + kf) * 64 + lane];
    for (int cg = 0; cg < 4; cg++) bv[cg] = bp[((size_t)(nt0 + cg) * 6 + kf) * 64 + lane];
    for (int a = 0; a < 4; a++)
      for (int cg = 0; cg < 4; cg++)
        acc[a][cg] = __builtin_amdgcn_mfma_f32_16x16x32_bf16(av[a], bv[cg], acc[a][cg], 0, 0, 0);
  }
  for (int cg = 0; cg < 4; cg++) {
    int n = (nt0 + cg) * 16 + col;
    float bias = kern_b[n];
    for (int a = 0; a < 4; a++) {
      int mbase = (mt0 + a) * 16 + q * 4;
      for (int r = 0; r < 4; r++)
        kbs[(size_t)(mbase + r) * LWN + n] = f2bf(acc[a][cg][r] + bias);
    }
  }
}

// ---------------- dilated conv as MFMA GEMM: M=131072, N=64, K=192 ----------------
__global__ __launch_bounds__(256) void dconv_kernel(const float* __restrict__ h,
                                                    const unsigned short* __restrict__ dwf,
                                                    const float* __restrict__ conv_b,
                                                    unsigned short* __restrict__ xc,
                                                    int lay, int d) {
  int tid = threadIdx.x;
  int w = tid >> 6, lane = tid & 63;
  int col = lane & 15, q = lane >> 4;
  int m0 = blockIdx.x * 256 + w * 64;
  int b = m0 >> 15, t0 = m0 & 32767;
  const float* hb = h + (((size_t)b) << 15) * 64;
  const s16x8* wf = (const s16x8*)(dwf + (size_t)lay * 24 * 512);

  f32x4 acc[4][4];
  for (int mt = 0; mt < 4; mt++)
    for (int cg = 0; cg < 4; cg++) acc[mt][cg] = (f32x4){0.f, 0.f, 0.f, 0.f};

#pragma unroll
  for (int kf = 0; kf < 6; kf++) {
    s16x8 bv[4];
#pragma unroll
    for (int cg = 0; cg < 4; cg++) bv[cg] = wf[(cg * 6 + kf) * 64 + lane];
    int k0 = kf * 32 + q * 8;
    int kk = k0 >> 6, i0 = k0 & 63;
    int dt = (kk - 1) * d;
    s16x8 ah[4], al[4];
#pragma unroll
    for (int mt = 0; mt < 4; mt++) {
      int t = t0 + mt * 16 + col + dt;
      bool oob = ((unsigned)t >= (unsigned)TSZ);
      int tc = oob ? 0 : t;
      f32x8 v = *(const f32x8*)(hb + (size_t)tc * 64 + i0);
#pragma unroll
      for (int j = 0; j < 8; j++) {
        float xv = oob ? 0.f : leaky(v[j]);
        unsigned short hi = f2bf(xv);
        ah[mt][j] = (short)hi;
        al[mt][j] = (short)f2bf(xv - bf2f(hi));
      }
    }
#pragma unroll
    for (int mt = 0; mt < 4; mt++)
#pragma unroll
      for (int cg = 0; cg < 4; cg++) {
        acc[mt][cg] = __builtin_amdgcn_mfma_f32_16x16x32_bf16(ah[mt], bv[cg], acc[mt][cg], 0, 0, 0);
        acc[mt][cg] = __builtin_amdgcn_mfma_f32_16x16x32_bf16(al[mt], bv[cg], acc[mt][cg], 0, 0, 0);
      }
  }

  unsigned short* xb = xc + (((size_t)b) << 15) * 64;
#pragma unroll
  for (int cg = 0; cg < 4; cg++) {
    int o = cg * 16 + col;
    float bias = conv_b[lay * 64 + o];
#pragma unroll
    for (int mt = 0; mt < 4; mt++)
#pragma unroll
      for (int r = 0; r < 4; r++) {
        int t = t0 + mt * 16 + q * 4 + r;
        xb[(size_t)t * 64 + o] = f2bf(leaky(acc[mt][cg][r] + bias));
      }
  }
}

// ---------------- LVC as per-(b,l) MFMA GEMM: M=256, N=128, K=192 ----------------
__global__ __launch_bounds__(512) void lvc_kernel(const unsigned short* __restrict__ xc,
                                                  const unsigned short* __restrict__ kbs,
                                                  const float* __restrict__ bbv,
                                                  float* __restrict__ h, int lay) {
  int tid = threadIdx.x;
  int l = blockIdx.x & 127, b = blockIdx.x >> 7;
  int w = tid >> 6, lane = tid & 63;
  int wm = w & 3, wn = w >> 2;
  int col = lane & 15, qq = lane >> 4;
  const unsigned short* srow =
      kbs + (size_t)(b * 128 + lay * 32 + (l >> 2)) * LWN + (l & 3) * 24576;
  const unsigned short* xb = xc + (((size_t)b) << 15) * 64;

  f32x4 acc[4][4];
  for (int mt = 0; mt < 4; mt++)
    for (int cg = 0; cg < 4; cg++) acc[mt][cg] = (f32x4){0.f, 0.f, 0.f, 0.f};

  s16x8 av[2][4], bv[2][4];
  const s16x8 zfrag = {0, 0, 0, 0, 0, 0, 0, 0};

#define LOAD_STEP(p, kf)                                                            \
  {                                                                                 \
    int k0 = (kf) * 32 + qq * 8;                                                    \
    int kk = k0 >> 6, i0 = k0 & 63;                                                 \
    _Pragma("unroll") for (int mt = 0; mt < 4; mt++) {                              \
      int s = wm * 64 + mt * 16 + col;                                              \
      int nr = 3 * s + kk - 255;                                                    \
      int n = nr < 0 ? -nr : (nr >= 258 ? 514 - nr : nr);                           \
      int t = l * 256 + n - 1;                                                      \
      bool oob = ((unsigned)t >= (unsigned)TSZ);                                    \
      int tc = oob ? 0 : t;                                                         \
      s16x8 v = *(const s16x8*)(xb + (size_t)tc * 64 + i0);                         \
      av[p][mt] = oob ? zfrag : v;                                                  \
    }                                                                               \
    _Pragma("unroll") for (int cg = 0; cg < 4; cg++) {                              \
      int nt = 2 * wn + (cg & 1) + ((cg >> 1) << 2);                                \
      int o = nt * 16 + col;                                                        \
      const unsigned short* bp = srow + i0 * 384 + o * 3 + kk;                      \
      s16x8 bvv;                                                                    \
      _Pragma("unroll") for (int j = 0; j < 8; j++) bvv[j] = (short)bp[j * 384];    \
      bv[p][cg] = bvv;                                                              \
    }                                                                               \
  }

  LOAD_STEP(0, 0)
#pragma unroll
  for (int kf = 0; kf < 6; kf++) {
    int cur = kf & 1, nxt = cur ^ 1;
    if (kf < 5) LOAD_STEP(nxt, kf + 1)
#pragma unroll
    for (int mt = 0; mt < 4; mt++)
#pragma unroll
      for (int cg = 0; cg < 4; cg++)
        acc[mt][cg] =
            __builtin_amdgcn_mfma_f32_16x16x32_bf16(av[cur][mt], bv[cur][cg], acc[mt][cg], 0, 0, 0);
  }
#undef LOAD_STEP

  // epilogue: bias + sigmoid*tanh gate + h residual update
  int lq = l >> 2, l2 = l & 3;
  const float* bb0 = bbv + (size_t)(b * 128 + lay * 32 + lq) * 512 + l2 * 128;
  float* hb = h + ((((size_t)b) << 15) + l * 256) * 64;
#pragma unroll
  for (int mt = 0; mt < 4; mt++) {
#pragma unroll
    for (int p = 0; p < 2; p++) {
      int o = (2 * wn + p) * 16 + col;
      float b0 = bb0[o], b1 = bb0[o + 64];
#pragma unroll
      for (int r = 0; r < 4; r++) {
        int s = wm * 64 + mt * 16 + qq * 4 + r;
        float a0 = acc[mt][p][r] + b0;
        float a1 = acc[mt][p + 2][r] + b1;
        float sg = 1.f / (1.f + __expf(-a0));
        float ex = __expf(2.f * a1);
        float th = 1.f - 2.f / (ex + 1.f);
        hb[(size_t)s * 64 + o] += sg * th;
      }
    }
  }
}

extern "C" void kernel_launch(void* const* d_in, const int* in_sizes, int n_in,
                              void* d_out, int out_size, void* d_ws, size_t ws_size,
                              hipStream_t stream) {
  (void)in_sizes; (void)n_in; (void)out_size; (void)ws_size;
  const float* x      = (const float*)d_in[0];
  const float* c      = (const float*)d_in[1];
  const float* ct_w   = (const float*)d_in[2];
  const float* ct_b   = (const float*)d_in[3];
  const float* conv_w = (const float*)d_in[4];
  const float* conv_b = (const float*)d_in[5];
  const float* inp_w  = (const float*)d_in[6];
  const float* inp_b  = (const float*)d_in[7];
  const float* res_w1 = (const float*)d_in[8];
  const float* res_b1 = (const float*)d_in[9];
  const float* res_w2 = (const float*)d_in[10];
  const float* res_b2 = (const float*)d_in[11];
  const float* kern_w = (const float*)d_in[12];
  const float* kern_b = (const float*)d_in[13];
  const float* bias_w = (const float*)d_in[14];
  const float* bias_b = (const float*)d_in[15];

  float* h = (float*)d_out;  // h lives in d_out (fully written by ctm_kernel)
  char* ws = (char*)d_ws;
  // region [0, 37748736): Wf during GEMM phase, then reused as bf16 xc in layer phase
  unsigned short* Wf = (unsigned short*)(ws);
  unsigned short* xc = (unsigned short*)(ws);
  unsigned short* kb = (unsigned short*)(ws + 37748736);   // 100663296 B (row-major [m][n] bf16)
  float* A           = (float*)(ws + 138412032);           // 393216 B
  unsigned short* Af = (unsigned short*)(ws + 138805248);  // 196608 B
  float* cc          = (float*)(ws + 139001856);           // 131072 B
  float* t1          = (float*)(ws + 139132928);           // 131072 B
  float* bbv         = (float*)(ws + 139264000);           // 1048576 B
  unsigned short* dwf = (unsigned short*)(ws + 140312576); // 98304 B
  // ctwf (262144 B) overlaps A/Af region: dead before patch_kernel writes A.
  unsigned short* ctwf = (unsigned short*)(ws + 138412032);

  ctwfrag_kernel<<<dim3(32), dim3(256), 0, stream>>>(ct_w, ctwf);
  ctm_kernel<<<dim3(512), dim3(256), 0, stream>>>(x, ctwf, ct_b, h);
  conv5_kernel<<<dim3(128), dim3(256), 0, stream>>>(c, inp_w, inp_b, cc);
  for (int j = 0; j < 3; j++) {
    conv3_kernel<0><<<dim3(128), dim3(256), 0, stream>>>(cc, res_w1 + j * 12288, res_b1 + j * 64,
                                                         (const float*)nullptr, t1);
    conv3_kernel<1><<<dim3(128), dim3(256), 0, stream>>>(t1, res_w2 + j * 12288, res_b2 + j * 64,
                                                         cc, cc);
  }
  patch_kernel<<<dim3(384), dim3(256), 0, stream>>>(cc, A);
  bbgemm_kernel<<<dim3(1024), dim3(256), 0, stream>>>(A, bias_w, bias_b, bbv);
  wreorg_kernel<<<dim3(9216), dim3(256), 0, stream>>>(kern_w, Wf);
  afrag_kernel<<<dim3(48), dim3(256), 0, stream>>>(A, Af);
  kgemm_kernel<<<dim3(1536, 2), dim3(256), 0, stream>>>(Af, Wf, kern_b, kb);
  dwfrag_kernel<<<dim3(24), dim3(256), 0, stream>>>(conv_w, dwf);

  const int dil[4] = {1, 3, 9, 27};
  for (int lay = 0; lay < 4; lay++) {
    dconv_kernel<<<dim3(512), dim3(256), 0, stream>>>(h, dwf, conv_b, xc, lay, dil[lay]);
    lvc_kernel<<<dim3(512), dim3(512), 0, stream>>>(xc, kb, bbv, h, lay);
  }
}

// Round 6
// 541.390 us; speedup vs baseline: 5.9560x; 1.0441x over previous
//
#include <hip/hip_runtime.h>

#define TSZ 32768
#define LWN 98304

typedef float f32x4 __attribute__((ext_vector_type(4)));
typedef float f32x8 __attribute__((ext_vector_type(8)));
typedef short s16x8 __attribute__((ext_vector_type(8)));
typedef unsigned short u16x8 __attribute__((ext_vector_type(8)));

__device__ __forceinline__ float leaky(float x) { return fmaxf(x, 0.2f * x); }
__device__ __forceinline__ float bf2f(unsigned short b) { return __uint_as_float(((unsigned)b) << 16); }
__device__ __forceinline__ unsigned short f2bf(float f) {
  unsigned u = __float_as_uint(f);
  u += 0x7fffu + ((u >> 16) & 1u);
  return (unsigned short)(u >> 16);
}

// truncation hi/lo split: hi = trunc-to-bf16(x), lo = trunc-to-bf16(x - hi).
// residual ~2^-16 rel; cheaper than round-to-nearest (no carry chain).
__device__ __forceinline__ void split_trunc(float xv, short& hi, short& lo) {
  unsigned bits = __float_as_uint(xv);
  hi = (short)(bits >> 16);
  float hif = __uint_as_float(bits & 0xffff0000u);
  lo = (short)(__float_as_uint(xv - hif) >> 16);
}

// ---------------- ct weights -> hi/lo B-fragment pairs (per phase) ----------------
__global__ __launch_bounds__(256) void ctwfrag_kernel(const float* __restrict__ ct_w,
                                                      unsigned short* __restrict__ ctwf) {
  int ft = blockIdx.x * 256 + threadIdx.x;  // 8192
  int lane = ft & 63, frag = ft >> 6;       // 128 frags
  int phi = frag >> 4, fr = frag & 15;
  int nt = fr >> 2, kf = fr & 3;
  int w0 = (11 - phi) & 7;
  int o = nt * 16 + (lane & 15);
  int k0 = kf * 32 + (lane >> 4) * 8;
  u16x8 vh, vl;
  for (int j = 0; j < 8; j++) {
    int k = k0 + j, w2 = k >> 6, i = k & 63;
    float wv = ct_w[(w0 + 8 * w2) * 4096 + i * 64 + o];
    unsigned short hi = f2bf(wv);
    vh[j] = hi;
    vl[j] = f2bf(wv - bf2f(hi));
  }
  *(u16x8*)(ctwf + ((size_t)frag * 64 + lane) * 8) = vh;
  *(u16x8*)(ctwf + ((size_t)(frag + 128) * 64 + lane) * 8) = vl;
}

// ---------------- conv_transpose as MFMA GEMM (per phase): M=4096/b, N=64, K=128 ---
__global__ __launch_bounds__(256) void ctm_kernel(const float* __restrict__ x,
                                                  const unsigned short* __restrict__ ctwf,
                                                  const float* __restrict__ ct_b,
                                                  float* __restrict__ h) {
  int tid = threadIdx.x;
  int w = tid >> 6, lane = tid & 63;
  int col = lane & 15, q = lane >> 4;
  int bid = blockIdx.x;  // 512
  int blk = bid & 15, phi = (bid >> 4) & 7, b = bid >> 7;
  int w0 = (11 - phi) & 7;
  int d0 = (phi + w0 - 11) >> 3;  // -1 or 0
  int mm0 = blk * 256 + w * 64;
  const float* xb = x + (((size_t)b) << 12) * 64;
  const s16x8* wf = (const s16x8*)ctwf;

  f32x4 acc[4][4];
  for (int mt = 0; mt < 4; mt++)
    for (int cg = 0; cg < 4; cg++) acc[mt][cg] = (f32x4){0.f, 0.f, 0.f, 0.f};

#pragma unroll
  for (int kf = 0; kf < 4; kf++) {
    s16x8 bh[4], bl[4];
#pragma unroll
    for (int cg = 0; cg < 4; cg++) {
      int frag = (phi * 4 + cg) * 4 + kf;
      bh[cg] = wf[frag * 64 + lane];
      bl[cg] = wf[(frag + 128) * 64 + lane];
    }
    int k0 = kf * 32 + q * 8;
    int w2 = k0 >> 6, i0 = k0 & 63;
    int rb = mm0 + d0 + w2;
    s16x8 ah[4], al[4];
#pragma unroll
    for (int mt = 0; mt < 4; mt++) {
      int r = rb + mt * 16 + col;
      bool oob = ((unsigned)r >= 4096u);
      int rc = oob ? 0 : r;
      f32x8 v = *(const f32x8*)(xb + (size_t)rc * 64 + i0);
#pragma unroll
      for (int j = 0; j < 8; j++) {
        float xv = oob ? 0.f : leaky(v[j]);
        short hi, lo;
        split_trunc(xv, hi, lo);
        ah[mt][j] = hi;
        al[mt][j] = lo;
      }
    }
#pragma unroll
    for (int mt = 0; mt < 4; mt++)
#pragma unroll
      for (int cg = 0; cg < 4; cg++) {
        acc[mt][cg] = __builtin_amdgcn_mfma_f32_16x16x32_bf16(ah[mt], bh[cg], acc[mt][cg], 0, 0, 0);
        acc[mt][cg] = __builtin_amdgcn_mfma_f32_16x16x32_bf16(al[mt], bh[cg], acc[mt][cg], 0, 0, 0);
        acc[mt][cg] = __builtin_amdgcn_mfma_f32_16x16x32_bf16(ah[mt], bl[cg], acc[mt][cg], 0, 0, 0);
      }
  }

  float* hb = h + (((size_t)b) << 15) * 64;
#pragma unroll
  for (int cg = 0; cg < 4; cg++) {
    int o = cg * 16 + col;
    float bias = ct_b[o];
#pragma unroll
    for (int mt = 0; mt < 4; mt++)
#pragma unroll
      for (int r = 0; r < 4; r++) {
        int mm = mm0 + mt * 16 + q * 4 + r;
        int t = mm * 8 + phi;
        hb[(size_t)t * 64 + o] = acc[mt][cg][r] + bias;
      }
  }
}

// ---------------- conditioning network (tiny) -----------------
__global__ __launch_bounds__(256) void conv5_kernel(const float* __restrict__ c,
                                                    const float* __restrict__ w,
                                                    const float* __restrict__ bias,
                                                    float* __restrict__ cc) {
  int f = blockIdx.x * 256 + threadIdx.x;  // 32768
  int o = f & 63, t = (f >> 6) & 127, b = f >> 13;
  float acc = bias[o];
  for (int kk = 0; kk < 5; kk++) {
    int tt = t + kk - 2;
    if (tt < 0 || tt >= 128) continue;
    const float* cr = c + (b * 128 + tt) * 80;
    const float* wr = w + kk * 80 * 64 + o;
    for (int i = 0; i < 80; i++) acc += cr[i] * wr[i * 64];
  }
  cc[f] = leaky(acc);
}

template <int ADD>
__global__ __launch_bounds__(256) void conv3_kernel(const float* __restrict__ xin,
                                                    const float* __restrict__ w,
                                                    const float* __restrict__ bias,
                                                    const float* __restrict__ addsrc,
                                                    float* __restrict__ out) {
  int f = blockIdx.x * 256 + threadIdx.x;  // 32768
  int o = f & 63, t = (f >> 6) & 127, b = f >> 13;
  float acc = bias[o];
  for (int kk = 0; kk < 3; kk++) {
    int tt = t + kk - 1;
    if (tt < 0 || tt >= 128) continue;
    const float* xr = xin + (b * 128 + tt) * 64;
    const float* wr = w + kk * 64 * 64 + o;
    for (int i = 0; i < 64; i++) acc += xr[i] * wr[i * 64];
  }
  float v = leaky(acc);
  if (ADD) v += addsrc[f];
  out[f] = v;
}

// ---------------- im2col patches for the prediction GEMMs -----------------
__global__ __launch_bounds__(256) void patch_kernel(const float* __restrict__ cc,
                                                    float* __restrict__ A) {
  int f = blockIdx.x * 256 + threadIdx.x;  // 98304
  int k = f % 192, m = f / 192;
  int b = m >> 7, l = m & 127;
  int kk = k >> 6, hh = k & 63;
  int ll = l + kk - 1;
  A[f] = (ll >= 0 && ll < 128) ? cc[((b << 7) + ll) * 64 + hh] : 0.f;
}

__global__ __launch_bounds__(256) void bbgemm_kernel(const float* __restrict__ A,
                                                     const float* __restrict__ w,
                                                     const float* __restrict__ bias,
                                                     float* __restrict__ bb) {
  int f = blockIdx.x * 256 + threadIdx.x;  // 262144
  int n = f & 511, m = f >> 9;
  float acc = bias[n];
  const float* ar = A + m * 192;
  const float* wr = w + n;
  for (int k = 0; k < 192; k++) acc += ar[k] * wr[k * 512];
  bb[f] = acc;
}

// ---------------- pre-swizzle W and A into MFMA fragment layout (bf16) ----------
__global__ __launch_bounds__(256) void wreorg_kernel(const float* __restrict__ W,
                                                     unsigned short* __restrict__ Wf) {
  int ft = blockIdx.x * 256 + threadIdx.x;  // 2359296
  int lane = ft & 63, fragid = ft >> 6;
  int kf = fragid % 6, nt = fragid / 6;
  int col = lane & 15, q = lane >> 4;
  int n = nt * 16 + col;
  u16x8 v;
  for (int j = 0; j < 8; j++) {
    int kki = kf * 32 + q * 8 + j;
    v[j] = f2bf(W[(size_t)kki * LWN + n]);
  }
  *(u16x8*)(Wf + ((size_t)fragid * 64 + lane) * 8) = v;
}

__global__ __launch_bounds__(256) void afrag_kernel(const float* __restrict__ A,
                                                    unsigned short* __restrict__ Af) {
  int ft = blockIdx.x * 256 + threadIdx.x;  // 12288
  int lane = ft & 63, fragid = ft >> 6;
  int kf = fragid % 6, mt = fragid / 6;
  int row = lane & 15, q = lane >> 4;
  const float* ar = A + (mt * 16 + row) * 192 + kf * 32 + q * 8;
  u16x8 v;
  for (int j = 0; j < 8; j++) v[j] = f2bf(ar[j]);
  *(u16x8*)(Af + ((size_t)fragid * 64 + lane) * 8) = v;
}

// ---------------- dconv weights -> B-fragment layout (all 4 layers, built once) ----
__global__ __launch_bounds__(256) void dwfrag_kernel(const float* __restrict__ conv_w,
                                                     unsigned short* __restrict__ dwf) {
  int ft = blockIdx.x * 256 + threadIdx.x;  // 6144
  int lane = ft & 63, frag = ft >> 6;       // 96 frags
  int lay = frag / 24, fr = frag % 24;
  int nt = fr / 6, kf = fr % 6;
  int o = nt * 16 + (lane & 15);
  int k0 = kf * 32 + (lane >> 4) * 8;
  u16x8 v;
  for (int j = 0; j < 8; j++) {
    int k = k0 + j, kk = k >> 6, i = k & 63;
    v[j] = f2bf(conv_w[lay * 12288 + kk * 4096 + i * 64 + o]);
  }
  *(u16x8*)(dwf + ((size_t)frag * 64 + lane) * 8) = v;
}

// ---------------- k = A @ W + kern_b  (M=512, N=98304, K=192), bf16 MFMA ----------
// Epilogue stages the 256x64 bf16 C-tile in LDS (row stride 68 shorts: +136B ==
// +8 banks/row -> conflict-free scatter writes), then 8 consecutive lanes emit
// 128B-contiguous rows (full L2 lines, 8 u16x8 stores/thread vs 64 2B stores).
__global__ __launch_bounds__(256) void kgemm_kernel(const unsigned short* __restrict__ Af,
                                                    const unsigned short* __restrict__ Wf,
                                                    const float* __restrict__ kern_b,
                                                    unsigned short* __restrict__ kbs) {
  __shared__ unsigned short cl[256 * 68];
  int tid = threadIdx.x;
  int wave = tid >> 6, lane = tid & 63;
  int col = lane & 15, q = lane >> 4;
  int mt0 = blockIdx.y * 16 + wave * 4;
  int nt0 = blockIdx.x * 4;
  f32x4 acc[4][4];
  for (int a = 0; a < 4; a++)
    for (int cg = 0; cg < 4; cg++) acc[a][cg] = (f32x4){0.f, 0.f, 0.f, 0.f};
  const s16x8* ap = (const s16x8*)Af;
  const s16x8* bp = (const s16x8*)Wf;
  for (int kf = 0; kf < 6; kf++) {
    s16x8 av[4], bv[4];
    for (int a = 0; a < 4; a++) av[a] = ap[((mt0 + a) * 6 + kf) * 64 + lane];
    for (int cg = 0; cg < 4; cg++) bv[cg] = bp[((size_t)(nt0 + cg) * 6 + kf) * 64 + lane];
    for (int a = 0; a < 4; a++)
      for (int cg = 0; cg < 4; cg++)
        acc[a][cg] = __builtin_amdgcn_mfma_f32_16x16x32_bf16(av[a], bv[cg], acc[a][cg], 0, 0, 0);
  }
  for (int cg = 0; cg < 4; cg++) {
    float bias = kern_b[(nt0 + cg) * 16 + col];
    for (int a = 0; a < 4; a++) {
      int lr0 = wave * 64 + a * 16 + q * 4;
      for (int r = 0; r < 4; r++)
        cl[(lr0 + r) * 68 + cg * 16 + col] = f2bf(acc[a][cg][r] + bias);
    }
  }
  __syncthreads();
  size_t mbase = (size_t)blockIdx.y * 256;
  int nbase = blockIdx.x * 64;
#pragma unroll
  for (int rep = 0; rep < 8; rep++) {
    int cid = rep * 256 + tid;
    int row = cid >> 3, ch = cid & 7;
    u16x8 vv = *(const u16x8*)(cl + row * 68 + ch * 8);
    *(u16x8*)(kbs + (mbase + row) * LWN + nbase + ch * 8) = vv;
  }
}

// ---------------- dilated conv as MFMA GEMM: M=131072, N=64, K=192 ----------------
__global__ __launch_bounds__(256) void dconv_kernel(const float* __restrict__ h,
                                                    const unsigned short* __restrict__ dwf,
                                                    const float* __restrict__ conv_b,
                                                    unsigned short* __restrict__ xc,
                                                    int lay, int d) {
  int tid = threadIdx.x;
  int w = tid >> 6, lane = tid & 63;
  int col = lane & 15, q = lane >> 4;
  int m0 = blockIdx.x * 256 + w * 64;
  int b = m0 >> 15, t0 = m0 & 32767;
  const float* hb = h + (((size_t)b) << 15) * 64;
  const s16x8* wf = (const s16x8*)(dwf + (size_t)lay * 24 * 512);

  f32x4 acc[4][4];
  for (int mt = 0; mt < 4; mt++)
    for (int cg = 0; cg < 4; cg++) acc[mt][cg] = (f32x4){0.f, 0.f, 0.f, 0.f};

#pragma unroll
  for (int kf = 0; kf < 6; kf++) {
    s16x8 bv[4];
#pragma unroll
    for (int cg = 0; cg < 4; cg++) bv[cg] = wf[(cg * 6 + kf) * 64 + lane];
    int k0 = kf * 32 + q * 8;
    int kk = k0 >> 6, i0 = k0 & 63;
    int dt = (kk - 1) * d;
    s16x8 ah[4], al[4];
#pragma unroll
    for (int mt = 0; mt < 4; mt++) {
      int t = t0 + mt * 16 + col + dt;
      bool oob = ((unsigned)t >= (unsigned)TSZ);
      int tc = oob ? 0 : t;
      f32x8 v = *(const f32x8*)(hb + (size_t)tc * 64 + i0);
#pragma unroll
      for (int j = 0; j < 8; j++) {
        float xv = oob ? 0.f : leaky(v[j]);
        short hi, lo;
        split_trunc(xv, hi, lo);
        ah[mt][j] = hi;
        al[mt][j] = lo;
      }
    }
#pragma unroll
    for (int mt = 0; mt < 4; mt++)
#pragma unroll
      for (int cg = 0; cg < 4; cg++) {
        acc[mt][cg] = __builtin_amdgcn_mfma_f32_16x16x32_bf16(ah[mt], bv[cg], acc[mt][cg], 0, 0, 0);
        acc[mt][cg] = __builtin_amdgcn_mfma_f32_16x16x32_bf16(al[mt], bv[cg], acc[mt][cg], 0, 0, 0);
      }
  }

  unsigned short* xb = xc + (((size_t)b) << 15) * 64;
#pragma unroll
  for (int cg = 0; cg < 4; cg++) {
    int o = cg * 16 + col;
    float bias = conv_b[lay * 64 + o];
#pragma unroll
    for (int mt = 0; mt < 4; mt++)
#pragma unroll
      for (int r = 0; r < 4; r++) {
        int t = t0 + mt * 16 + q * 4 + r;
        xb[(size_t)t * 64 + o] = f2bf(leaky(acc[mt][cg][r] + bias));
      }
  }
}

// ---------------- LVC as per-(b,l) MFMA GEMM: M=256, N=128, K=192 ----------------
__global__ __launch_bounds__(512) void lvc_kernel(const unsigned short* __restrict__ xc,
                                                  const unsigned short* __restrict__ kbs,
                                                  const float* __restrict__ bbv,
                                                  float* __restrict__ h, int lay) {
  int tid = threadIdx.x;
  int l = blockIdx.x & 127, b = blockIdx.x >> 7;
  int w = tid >> 6, lane = tid & 63;
  int wm = w & 3, wn = w >> 2;
  int col = lane & 15, qq = lane >> 4;
  const unsigned short* srow =
      kbs + (size_t)(b * 128 + lay * 32 + (l >> 2)) * LWN + (l & 3) * 24576;
  const unsigned short* xb = xc + (((size_t)b) << 15) * 64;

  f32x4 acc[4][4];
  for (int mt = 0; mt < 4; mt++)
    for (int cg = 0; cg < 4; cg++) acc[mt][cg] = (f32x4){0.f, 0.f, 0.f, 0.f};

  s16x8 av[2][4], bv[2][4];
  const s16x8 zfrag = {0, 0, 0, 0, 0, 0, 0, 0};

#define LOAD_STEP(p, kf)                                                            \
  {                                                                                 \
    int k0 = (kf) * 32 + qq * 8;                                                    \
    int kk = k0 >> 6, i0 = k0 & 63;                                                 \
    _Pragma("unroll") for (int mt = 0; mt < 4; mt++) {                              \
      int s = wm * 64 + mt * 16 + col;                                              \
      int nr = 3 * s + kk - 255;                                                    \
      int n = nr < 0 ? -nr : (nr >= 258 ? 514 - nr : nr);                           \
      int t = l * 256 + n - 1;                                                      \
      bool oob = ((unsigned)t >= (unsigned)TSZ);                                    \
      int tc = oob ? 0 : t;                                                         \
      s16x8 v = *(const s16x8*)(xb + (size_t)tc * 64 + i0);                         \
      av[p][mt] = oob ? zfrag : v;                                                  \
    }                                                                               \
    _Pragma("unroll") for (int cg = 0; cg < 4; cg++) {                              \
      int nt = 2 * wn + (cg & 1) + ((cg >> 1) << 2);                                \
      int o = nt * 16 + col;                                                        \
      const unsigned short* bp = srow + i0 * 384 + o * 3 + kk;                      \
      s16x8 bvv;                                                                    \
      _Pragma("unroll") for (int j = 0; j < 8; j++) bvv[j] = (short)bp[j * 384];    \
      bv[p][cg] = bvv;                                                              \
    }                                                                               \
  }

  LOAD_STEP(0, 0)
#pragma unroll
  for (int kf = 0; kf < 6; kf++) {
    int cur = kf & 1, nxt = cur ^ 1;
    if (kf < 5) LOAD_STEP(nxt, kf + 1)
#pragma unroll
    for (int mt = 0; mt < 4; mt++)
#pragma unroll
      for (int cg = 0; cg < 4; cg++)
        acc[mt][cg] =
            __builtin_amdgcn_mfma_f32_16x16x32_bf16(av[cur][mt], bv[cur][cg], acc[mt][cg], 0, 0, 0);
  }
#undef LOAD_STEP

  // epilogue: bias + sigmoid*tanh gate + h residual update
  int lq = l >> 2, l2 = l & 3;
  const float* bb0 = bbv + (size_t)(b * 128 + lay * 32 + lq) * 512 + l2 * 128;
  float* hb = h + ((((size_t)b) << 15) + l * 256) * 64;
#pragma unroll
  for (int mt = 0; mt < 4; mt++) {
#pragma unroll
    for (int p = 0; p < 2; p++) {
      int o = (2 * wn + p) * 16 + col;
      float b0 = bb0[o], b1 = bb0[o + 64];
#pragma unroll
      for (int r = 0; r < 4; r++) {
        int s = wm * 64 + mt * 16 + qq * 4 + r;
        float a0 = acc[mt][p][r] + b0;
        float a1 = acc[mt][p + 2][r] + b1;
        float sg = 1.f / (1.f + __expf(-a0));
        float ex = __expf(2.f * a1);
        float th = 1.f - 2.f / (ex + 1.f);
        hb[(size_t)s * 64 + o] += sg * th;
      }
    }
  }
}

extern "C" void kernel_launch(void* const* d_in, const int* in_sizes, int n_in,
                              void* d_out, int out_size, void* d_ws, size_t ws_size,
                              hipStream_t stream) {
  (void)in_sizes; (void)n_in; (void)out_size; (void)ws_size;
  const float* x      = (const float*)d_in[0];
  const float* c      = (const float*)d_in[1];
  const float* ct_w   = (const float*)d_in[2];
  const float* ct_b   = (const float*)d_in[3];
  const float* conv_w = (const float*)d_in[4];
  const float* conv_b = (const float*)d_in[5];
  const float* inp_w  = (const float*)d_in[6];
  const float* inp_b  = (const float*)d_in[7];
  const float* res_w1 = (const float*)d_in[8];
  const float* res_b1 = (const float*)d_in[9];
  const float* res_w2 = (const float*)d_in[10];
  const float* res_b2 = (const float*)d_in[11];
  const float* kern_w = (const float*)d_in[12];
  const float* kern_b = (const float*)d_in[13];
  const float* bias_w = (const float*)d_in[14];
  const float* bias_b = (const float*)d_in[15];

  float* h = (float*)d_out;  // h lives in d_out (fully written by ctm_kernel)
  char* ws = (char*)d_ws;
  // region [0, 37748736): Wf during GEMM phase, then reused as bf16 xc in layer phase
  unsigned short* Wf = (unsigned short*)(ws);
  unsigned short* xc = (unsigned short*)(ws);
  unsigned short* kb = (unsigned short*)(ws + 37748736);   // 100663296 B (row-major [m][n] bf16)
  float* A           = (float*)(ws + 138412032);           // 393216 B
  unsigned short* Af = (unsigned short*)(ws + 138805248);  // 196608 B
  float* cc          = (float*)(ws + 139001856);           // 131072 B
  float* t1          = (float*)(ws + 139132928);           // 131072 B
  float* bbv         = (float*)(ws + 139264000);           // 1048576 B
  unsigned short* dwf = (unsigned short*)(ws + 140312576); // 98304 B
  // ctwf (262144 B) overlaps A/Af region: dead before patch_kernel writes A.
  unsigned short* ctwf = (unsigned short*)(ws + 138412032);

  ctwfrag_kernel<<<dim3(32), dim3(256), 0, stream>>>(ct_w, ctwf);
  ctm_kernel<<<dim3(512), dim3(256), 0, stream>>>(x, ctwf, ct_b, h);
  conv5_kernel<<<dim3(128), dim3(256), 0, stream>>>(c, inp_w, inp_b, cc);
  for (int j = 0; j < 3; j++) {
    conv3_kernel<0><<<dim3(128), dim3(256), 0, stream>>>(cc, res_w1 + j * 12288, res_b1 + j * 64,
                                                         (const float*)nullptr, t1);
    conv3_kernel<1><<<dim3(128), dim3(256), 0, stream>>>(t1, res_w2 + j * 12288, res_b2 + j * 64,
                                                         cc, cc);
  }
  patch_kernel<<<dim3(384), dim3(256), 0, stream>>>(cc, A);
  bbgemm_kernel<<<dim3(1024), dim3(256), 0, stream>>>(A, bias_w, bias_b, bbv);
  wreorg_kernel<<<dim3(9216), dim3(256), 0, stream>>>(kern_w, Wf);
  afrag_kernel<<<dim3(48), dim3(256), 0, stream>>>(A, Af);
  kgemm_kernel<<<dim3(1536, 2), dim3(256), 0, stream>>>(Af, Wf, kern_b, kb);
  dwfrag_kernel<<<dim3(24), dim3(256), 0, stream>>>(conv_w, dwf);

  const int dil[4] = {1, 3, 9, 27};
  for (int lay = 0; lay < 4; lay++) {
    dconv_kernel<<<dim3(512), dim3(256), 0, stream>>>(h, dwf, conv_b, xc, lay, dil[lay]);
    lvc_kernel<<<dim3(512), dim3(512), 0, stream>>>(xc, kb, bbv, h, lay);
  }
}